// Round 8
// baseline (361.027 us; speedup 1.0000x reference)
//
#include <hip/hip_runtime.h>
#include <math.h>

#define BB    4
#define TT    1024
#define DD    512
#define NH    8
#define DH    64
#define BH    32          // BB*NH
#define INV_TAU 10.0f

typedef __attribute__((ext_vector_type(8))) short short8;
typedef __attribute__((ext_vector_type(4))) float f4;

__device__ inline unsigned short f2bf(float f) {
  unsigned u = __float_as_uint(f);
  u += 0x7FFFu + ((u >> 16) & 1u);        // round-to-nearest-even
  return (unsigned short)(u >> 16);
}
__device__ inline float bf2f(unsigned short h) {
  return __uint_as_float(((unsigned)h) << 16);
}

// ---------------------------------------------------------------------------
// P1: split x (fp32 [4096][512]) into bf16 hi/lo planes (same layout).
// ---------------------------------------------------------------------------
__global__ __launch_bounds__(256) void k_split_x(
    const float* __restrict__ x, unsigned short* __restrict__ xh,
    unsigned short* __restrict__ xl)
{
  const int i = (blockIdx.x * 256 + threadIdx.x) * 4;
  float4 v = *(const float4*)&x[i];
  ushort4 h, l;
  h.x = f2bf(v.x); l.x = f2bf(v.x - bf2f(h.x));
  h.y = f2bf(v.y); l.y = f2bf(v.y - bf2f(h.y));
  h.z = f2bf(v.z); l.z = f2bf(v.z - bf2f(h.z));
  h.w = f2bf(v.w); l.w = f2bf(v.w - bf2f(h.w));
  *(ushort4*)&xh[i] = h;
  *(ushort4*)&xl[i] = l;
}

// ---------------------------------------------------------------------------
// P2: transpose + split W -> wth/wtl [1536][512] bf16, k-contiguous rows.
// ---------------------------------------------------------------------------
__global__ __launch_bounds__(256) void k_split_wt(
    const float* __restrict__ wq, const float* __restrict__ wk,
    const float* __restrict__ wv, unsigned short* __restrict__ wth,
    unsigned short* __restrict__ wtl)
{
  __shared__ float Wf[64][65];
  const int ten = blockIdx.z;
  const float* W = (ten == 0) ? wq : ((ten == 1) ? wk : wv);
  const int n0 = blockIdx.x * 64, k0 = blockIdx.y * 64;
  const int tid = threadIdx.x;
#pragma unroll
  for (int p = 0; p < 4; ++p) {
    int kk = p * 16 + (tid >> 4);
    int nn = (tid & 15) * 4;
    float4 v = *(const float4*)&W[(size_t)(k0 + kk) * 512 + n0 + nn];
    Wf[kk][nn + 0] = v.x; Wf[kk][nn + 1] = v.y;
    Wf[kk][nn + 2] = v.z; Wf[kk][nn + 3] = v.w;
  }
  __syncthreads();
  const int n = tid >> 2, kq = tid & 3;
  size_t base = ((size_t)(ten * 512 + n0 + n)) * 512 + k0 + kq * 16;
#pragma unroll
  for (int jj = 0; jj < 4; ++jj) {
    ushort4 h, l;
    float f0 = Wf[kq * 16 + jj * 4 + 0][n];
    float f1 = Wf[kq * 16 + jj * 4 + 1][n];
    float f2 = Wf[kq * 16 + jj * 4 + 2][n];
    float f3 = Wf[kq * 16 + jj * 4 + 3][n];
    h.x = f2bf(f0); l.x = f2bf(f0 - bf2f(h.x));
    h.y = f2bf(f1); l.y = f2bf(f1 - bf2f(h.y));
    h.z = f2bf(f2); l.z = f2bf(f2 - bf2f(h.z));
    h.w = f2bf(f3); l.w = f2bf(f3 - bf2f(h.w));
    *(ushort4*)&wth[base + jj * 4] = h;
    *(ushort4*)&wtl[base + jj * 4] = l;
  }
}

// ---------------------------------------------------------------------------
// K1: QKV projection via bf16x3 MFMA + fused per-head softmax.
// ---------------------------------------------------------------------------
__global__ __launch_bounds__(256) void k_proj_mfma(
    const unsigned short* __restrict__ xh, const unsigned short* __restrict__ xl,
    const unsigned short* __restrict__ wth, const unsigned short* __restrict__ wtl,
    unsigned short* __restrict__ qh, unsigned short* __restrict__ ql,
    unsigned short* __restrict__ kh, unsigned short* __restrict__ kl,
    float* __restrict__ vs)
{
  __shared__ unsigned short Ah[128][40];
  __shared__ unsigned short Al[128][40];
  __shared__ unsigned short Bh[128][40];
  __shared__ unsigned short Bl[128][40];
  const int tid = threadIdx.x;
  const int n0g = blockIdx.x * 128;
  const int m0 = blockIdx.y * 128;
  const int w = tid >> 6, lane = tid & 63;
  const int mw = (w & 1) * 64, nw = (w >> 1) * 64;
  const int quad = lane >> 4, l16 = lane & 15;
  const int srow = tid >> 2;
  const int sk = (tid & 3) * 8;

  f4 acc[4][4] = {};

  for (int k0 = 0; k0 < DD; k0 += 32) {
    short8 a0 = *(const short8*)&xh[(size_t)(m0 + srow) * DD + k0 + sk];
    short8 a1 = *(const short8*)&xh[(size_t)(m0 + 64 + srow) * DD + k0 + sk];
    short8 a2 = *(const short8*)&xl[(size_t)(m0 + srow) * DD + k0 + sk];
    short8 a3 = *(const short8*)&xl[(size_t)(m0 + 64 + srow) * DD + k0 + sk];
    short8 b0 = *(const short8*)&wth[(size_t)(n0g + srow) * DD + k0 + sk];
    short8 b1 = *(const short8*)&wth[(size_t)(n0g + 64 + srow) * DD + k0 + sk];
    short8 b2 = *(const short8*)&wtl[(size_t)(n0g + srow) * DD + k0 + sk];
    short8 b3 = *(const short8*)&wtl[(size_t)(n0g + 64 + srow) * DD + k0 + sk];
    *(short8*)&Ah[srow][sk] = a0;  *(short8*)&Ah[64 + srow][sk] = a1;
    *(short8*)&Al[srow][sk] = a2;  *(short8*)&Al[64 + srow][sk] = a3;
    *(short8*)&Bh[srow][sk] = b0;  *(short8*)&Bh[64 + srow][sk] = b1;
    *(short8*)&Bl[srow][sk] = b2;  *(short8*)&Bl[64 + srow][sk] = b3;
    __syncthreads();

    short8 fbh[4], fbl[4];
#pragma unroll
    for (int nt = 0; nt < 4; ++nt) {
      fbh[nt] = *(const short8*)&Bh[nw + nt * 16 + l16][quad * 8];
      fbl[nt] = *(const short8*)&Bl[nw + nt * 16 + l16][quad * 8];
    }
#pragma unroll
    for (int mt = 0; mt < 4; ++mt) {
      short8 fah = *(const short8*)&Ah[mw + mt * 16 + l16][quad * 8];
      short8 fal = *(const short8*)&Al[mw + mt * 16 + l16][quad * 8];
#pragma unroll
      for (int nt = 0; nt < 4; ++nt) {
        acc[mt][nt] = __builtin_amdgcn_mfma_f32_16x16x32_bf16(fah, fbh[nt], acc[mt][nt], 0, 0, 0);
        acc[mt][nt] = __builtin_amdgcn_mfma_f32_16x16x32_bf16(fah, fbl[nt], acc[mt][nt], 0, 0, 0);
        acc[mt][nt] = __builtin_amdgcn_mfma_f32_16x16x32_bf16(fal, fbh[nt], acc[mt][nt], 0, 0, 0);
      }
    }
    __syncthreads();
  }

  const int tensor = n0g >> 9;
  const int ncol = (n0g & 511) + nw;
  const int h = ncol >> 6;
#pragma unroll
  for (int mt = 0; mt < 4; ++mt) {
#pragma unroll
    for (int r = 0; r < 4; ++r) {
      float v0 = acc[mt][0][r], v1 = acc[mt][1][r];
      float v2 = acc[mt][2][r], v3 = acc[mt][3][r];
      float mx = fmaxf(fmaxf(v0, v1), fmaxf(v2, v3));
#pragma unroll
      for (int msk = 1; msk <= 8; msk <<= 1) mx = fmaxf(mx, __shfl_xor(mx, msk, 64));
      float e0 = __expf((v0 - mx) * INV_TAU);
      float e1 = __expf((v1 - mx) * INV_TAU);
      float e2 = __expf((v2 - mx) * INV_TAU);
      float e3 = __expf((v3 - mx) * INV_TAU);
      float sm = e0 + e1 + e2 + e3;
#pragma unroll
      for (int msk = 1; msk <= 8; msk <<= 1) sm += __shfl_xor(sm, msk, 64);
      float inv = 1.0f / sm;
      int row = m0 + mw + mt * 16 + quad * 4 + r;
      int b = row >> 10, t = row & 1023;
      size_t base = (((size_t)b * NH + h) * TT + t) * DH;
      float e[4] = {e0 * inv, e1 * inv, e2 * inv, e3 * inv};
      if (tensor == 2) {
#pragma unroll
        for (int c = 0; c < 4; ++c) vs[base + l16 + c * 16] = e[c];
      } else {
        unsigned short* oh = tensor ? kh : qh;
        unsigned short* ol = tensor ? kl : ql;
#pragma unroll
        for (int c = 0; c < 4; ++c) {
          unsigned short hh = f2bf(e[c]);
          oh[base + l16 + c * 16] = hh;
          ol[base + l16 + c * 16] = f2bf(e[c] - bf2f(hh));
        }
      }
    }
  }
}

// ---------------------------------------------------------------------------
// P3: transpose + split V: vs [z][t][d] fp32 -> vth/vtl [z][d][t] bf16.
// ---------------------------------------------------------------------------
__global__ __launch_bounds__(256) void k_vsplit(
    const float* __restrict__ vs, unsigned short* __restrict__ vth,
    unsigned short* __restrict__ vtl)
{
  __shared__ float Vf[64][65];
  const int z = blockIdx.y, t0 = blockIdx.x * 64;
  const int tid = threadIdx.x;
#pragma unroll
  for (int it = 0; it < 4; ++it) {
    int tl = it * 16 + (tid >> 4);
    int d4 = (tid & 15) * 4;
    float4 v = *(const float4*)&vs[((size_t)z * TT + t0 + tl) * DH + d4];
    Vf[tl][d4 + 0] = v.x; Vf[tl][d4 + 1] = v.y;
    Vf[tl][d4 + 2] = v.z; Vf[tl][d4 + 3] = v.w;
  }
  __syncthreads();
#pragma unroll
  for (int it = 0; it < 8; ++it) {
    int d = it * 8 + (tid >> 5);
    int t = (tid & 31) * 2;
    float a0 = Vf[t][d], a1 = Vf[t + 1][d];
    unsigned short h0 = f2bf(a0), h1 = f2bf(a1);
    unsigned short l0 = f2bf(a0 - bf2f(h0)), l1 = f2bf(a1 - bf2f(h1));
    size_t o = ((size_t)z * DH + d) * TT + t0 + t;
    ushort2 hh; hh.x = h0; hh.y = h1;
    ushort2 ll; ll.x = l0; ll.y = l1;
    *(ushort2*)&vth[o] = hh;
    *(ushort2*)&vtl[o] = ll;
  }
}

// ---------------------------------------------------------------------------
// K2: scores via bf16x3 MFMA. One wave per lower-tri 64x64 tile.
// ---------------------------------------------------------------------------
__global__ __launch_bounds__(256) void k_qk(
    const unsigned short* __restrict__ qh, const unsigned short* __restrict__ ql,
    const unsigned short* __restrict__ kh, const unsigned short* __restrict__ kl,
    float* __restrict__ A)
{
  const int tid = threadIdx.x;
  const int gid = blockIdx.x * 4 + (tid >> 6);
  const int z = gid / 136;
  const int lx = gid - z * 136;
  int ti = (int)((sqrtf(8.0f * lx + 1.0f) - 1.0f) * 0.5f);
  while ((ti + 1) * (ti + 2) / 2 <= lx) ++ti;
  while (ti * (ti + 1) / 2 > lx) --ti;
  const int tj = lx - ti * (ti + 1) / 2;
  const int i0 = ti * 64, j0 = tj * 64;
  const int lane = tid & 63;
  const int quad = lane >> 4, l16 = lane & 15;
  const size_t zb = (size_t)z * TT * DH;

  short8 fbh[4][2], fbl[4][2];
#pragma unroll
  for (int nt = 0; nt < 4; ++nt)
#pragma unroll
    for (int ks = 0; ks < 2; ++ks) {
      size_t o = zb + (size_t)(j0 + nt * 16 + l16) * DH + ks * 32 + quad * 8;
      fbh[nt][ks] = *(const short8*)&kh[o];
      fbl[nt][ks] = *(const short8*)&kl[o];
    }

  f4 acc[4][4] = {};
#pragma unroll
  for (int mt = 0; mt < 4; ++mt) {
    short8 fah[2], fal[2];
#pragma unroll
    for (int ks = 0; ks < 2; ++ks) {
      size_t o = zb + (size_t)(i0 + mt * 16 + l16) * DH + ks * 32 + quad * 8;
      fah[ks] = *(const short8*)&qh[o];
      fal[ks] = *(const short8*)&ql[o];
    }
#pragma unroll
    for (int nt = 0; nt < 4; ++nt)
#pragma unroll
      for (int ks = 0; ks < 2; ++ks) {
        acc[mt][nt] = __builtin_amdgcn_mfma_f32_16x16x32_bf16(fah[ks], fbh[nt][ks], acc[mt][nt], 0, 0, 0);
        acc[mt][nt] = __builtin_amdgcn_mfma_f32_16x16x32_bf16(fah[ks], fbl[nt][ks], acc[mt][nt], 0, 0, 0);
        acc[mt][nt] = __builtin_amdgcn_mfma_f32_16x16x32_bf16(fal[ks], fbh[nt][ks], acc[mt][nt], 0, 0, 0);
      }
  }

  float* Ab = A + (size_t)z * TT * TT;
#pragma unroll
  for (int mt = 0; mt < 4; ++mt)
#pragma unroll
    for (int nt = 0; nt < 4; ++nt)
#pragma unroll
      for (int r = 0; r < 4; ++r)
        Ab[(size_t)(i0 + mt * 16 + quad * 4 + r) * TT + j0 + nt * 16 + l16] = acc[mt][nt][r];
}

// ---------------------------------------------------------------------------
// K3: diagonal run-length scan — register-resident, 512-thr / 8-chunk build.
// Lesson from R7: at 1024 thr the compiler caps VGPR at 64 and spills s[].
// Here: 8 waves/block, __launch_bounds__(512,2) -> 2 waves/SIMD -> 256 VGPR
// cap; s[128] (<=128 rows/chunk) + overhead ~170 VGPR, no spill. One group
// per block, 512 blocks heavy-first, single HBM read + single write pass.
// ---------------------------------------------------------------------------
__global__ __launch_bounds__(512, 2) void k_scan(float* __restrict__ A)
{
  __shared__ float Ssum[8][64];
  __shared__ float Gmax[8][64];
  const int blk = blockIdx.x;              // 0..511
  const int xb = blk >> 5;                 // 0..15, heavy first
  const int z = blk & 31;
  const int lane = threadIdx.x & 63;
  const int w = threadIdx.x >> 6;          // chunk 0..7
  float* __restrict__ Ab = A + (size_t)z * TT * TT;
  const int dbase = xb * 64;
  const int d = dbase + lane;
  const int L = (TT - dbase) >> 3;         // 8..128 rows per chunk
  const int r0 = dbase + w * L;

  // Single read pass: chunk rows into registers + chunk sum.
  float s[128];
  float S = 0.0f;
#pragma unroll
  for (int t = 0; t < 128; ++t) {
    int i = r0 + t;
    bool act = (t < L) && (i >= d);
    size_t idx = act ? ((size_t)i * (TT + 1) - d) : 0;
    float v = Ab[idx];
    s[t] = act ? v : 0.0f;
    S += s[t];
  }
  Ssum[w][lane] = S;
  __syncthreads();

  float cs_in = 0.0f;
  for (int ww = 0; ww < w; ++ww) cs_in += Ssum[ww][lane];

  // chunk g-max from registers (guard t<L: phantom rows would inject
  // g = cs_final and corrupt the prefix max)
  {
    float lcs = 0.0f, gm = 0.0f;
#pragma unroll
    for (int t = 0; t < 128; ++t) {
      lcs += s[t];
      float g = (cs_in + lcs) * (1.0f - s[t]);
      if (t < L) gm = fmaxf(gm, g);
    }
    Gmax[w][lane] = gm;
  }
  __syncthreads();

  float m = 0.0f;
  for (int ww = 0; ww < w; ++ww) m = fmaxf(m, Gmax[ww][lane]);

  // Emit from registers (write-only pass).
  {
    float lcs = 0.0f;
#pragma unroll
    for (int t = 0; t < 128; ++t) {
      int i = r0 + t;
      bool act = (t < L) && (i >= d);
      lcs += s[t];
      float cs = cs_in + lcs;
      if (t < L) m = fmaxf(m, cs * (1.0f - s[t]));
      if (act) Ab[(size_t)i * (TT + 1) - d] = cs - m;
    }
  }
}

// ---------------------------------------------------------------------------
// K4: fused flash-style softmax(P)·V. One wave per 16-row band (64-thr
// blocks, 2048 of them, heavy tiles first for dynamic balancing).
// ---------------------------------------------------------------------------
__global__ __launch_bounds__(64) void k_pv(
    const float* __restrict__ A, const unsigned short* __restrict__ vth,
    const unsigned short* __restrict__ vtl, float* __restrict__ oatt)
{
  const int lane = threadIdx.x;
  const int quad = lane >> 4, l16 = lane & 15;
  const int blk = blockIdx.x;              // 0..2047
  const int z = blk & 31;
  const int r = blk >> 5;                  // 0..63
  const int ti = 15 - (r >> 2);            // heavy (ti=15) first
  const int band = r & 3;
  const float* Az = A + (size_t)z * TT * TT;
  const unsigned short* vh = vth + (size_t)z * DH * TT;
  const unsigned short* vl = vtl + (size_t)z * DH * TT;

  const int i0 = ti * 64;
  const int irow = i0 + band * 16 + l16;   // this lane's P-row
  const float invi = 1.0f / (float)(irow + 1);
  f4 acc[4] = {};
  float m_old = -3e38f, l_run = 0.0f;

  for (int jt = 0; jt <= ti; ++jt) {
    float sc[16];
#pragma unroll
    for (int ks = 0; ks < 2; ++ks) {
      f4 s0 = *(const f4*)&Az[(size_t)irow * TT + jt * 64 + ks * 32 + quad * 8];
      f4 s1 = *(const f4*)&Az[(size_t)irow * TT + jt * 64 + ks * 32 + quad * 8 + 4];
#pragma unroll
      for (int u = 0; u < 4; ++u) { sc[ks * 8 + u] = s0[u]; sc[ks * 8 + 4 + u] = s1[u]; }
    }
#pragma unroll
    for (int u = 0; u < 16; ++u) {
      int j = jt * 64 + (u >> 3) * 32 + quad * 8 + (u & 7);
      float v = sc[u] + (float)j * invi;
      sc[u] = (j <= irow) ? v : -3e38f;
    }
    float mt_ = sc[0];
#pragma unroll
    for (int u = 1; u < 16; ++u) mt_ = fmaxf(mt_, sc[u]);
    mt_ = fmaxf(mt_, __shfl_xor(mt_, 16, 64));
    mt_ = fmaxf(mt_, __shfl_xor(mt_, 32, 64));
    float m_new = fmaxf(m_old, mt_);
    float alpha = __expf((m_old - m_new) * INV_TAU);
    unsigned short ph[16], pl[16];
    float ls = 0.0f;
#pragma unroll
    for (int u = 0; u < 16; ++u) {
      float pvv = __expf((sc[u] - m_new) * INV_TAU);
      unsigned short hh = f2bf(pvv);
      ph[u] = hh; pl[u] = f2bf(pvv - bf2f(hh));
      ls += pvv;
    }
    ls += __shfl_xor(ls, 16, 64);
    ls += __shfl_xor(ls, 32, 64);
    l_run = l_run * alpha + ls;
    m_old = m_new;
#pragma unroll
    for (int rr = 0; rr < 4; ++rr) {
      float ar = __shfl(alpha, quad * 4 + rr, 64);
#pragma unroll
      for (int nt = 0; nt < 4; ++nt) acc[nt][rr] *= ar;
    }
#pragma unroll
    for (int ks = 0; ks < 2; ++ks) {
      short8 pah, pal;
#pragma unroll
      for (int u = 0; u < 8; ++u) { pah[u] = (short)ph[ks * 8 + u]; pal[u] = (short)pl[ks * 8 + u]; }
#pragma unroll
      for (int nt = 0; nt < 4; ++nt) {
        size_t vo = (size_t)(nt * 16 + l16) * TT + jt * 64 + ks * 32 + quad * 8;
        short8 fvh = *(const short8*)&vh[vo];
        short8 fvl = *(const short8*)&vl[vo];
        acc[nt] = __builtin_amdgcn_mfma_f32_16x16x32_bf16(pah, fvh, acc[nt], 0, 0, 0);
        acc[nt] = __builtin_amdgcn_mfma_f32_16x16x32_bf16(pah, fvl, acc[nt], 0, 0, 0);
        acc[nt] = __builtin_amdgcn_mfma_f32_16x16x32_bf16(pal, fvh, acc[nt], 0, 0, 0);
      }
    }
  }
#pragma unroll
  for (int rr = 0; rr < 4; ++rr) {
    float lr = __shfl(l_run, quad * 4 + rr, 64);
    float inv = 1.0f / lr;
    int orow = i0 + band * 16 + quad * 4 + rr;
#pragma unroll
    for (int nt = 0; nt < 4; ++nt)
      oatt[((size_t)z * TT + orow) * DH + nt * 16 + l16] = acc[nt][rr] * inv;
  }
}

// ---------------------------------------------------------------------------
// K6: per-head output projection. 16 rows/block (W-tile amortized 4x,
// 4 independent FMA chains/thread — measured ~29 us win in R7).
// ---------------------------------------------------------------------------
__global__ __launch_bounds__(256) void k_oproj(
    const float* __restrict__ oatt, const float* __restrict__ wo,
    float* __restrict__ out)
{
  __shared__ float Wl[64][64];
  __shared__ float Ol[16][64];
  const int z = blockIdx.y;                // b*NH + h
  const int t0 = blockIdx.x * 16;
  const int b = z >> 3, h = z & 7;
  const int tid = threadIdx.x;
  const float* wb = wo + (size_t)h * 64 * 64;
#pragma unroll
  for (int u = 0; u < 4; ++u) {
    int q = tid + 256 * u;
    int dd = q >> 4, e4 = (q & 15) * 4;
    *(float4*)&Wl[dd][e4] = *(const float4*)&wb[(size_t)dd * 64 + e4];
  }
  {
    int rr = tid >> 4, d4 = (tid & 15) * 4;
    *(float4*)&Ol[rr][d4] = *(const float4*)&oatt[((size_t)z * TT + t0 + rr) * DH + d4];
  }
  __syncthreads();
  const int rg = tid >> 6, e = tid & 63;   // wave rg handles rows rg*4..rg*4+3
  float a0 = 0, a1 = 0, a2 = 0, a3 = 0;
#pragma unroll
  for (int dd = 0; dd < 64; ++dd) {
    float wv = Wl[dd][e];
    a0 += Ol[rg * 4 + 0][dd] * wv;
    a1 += Ol[rg * 4 + 1][dd] * wv;
    a2 += Ol[rg * 4 + 2][dd] * wv;
    a3 += Ol[rg * 4 + 3][dd] * wv;
  }
  size_t ob = ((size_t)b * TT + t0 + rg * 4) * DD + h * 64 + e;
  out[ob] = a0; out[ob + DD] = a1; out[ob + 2 * DD] = a2; out[ob + 3 * DD] = a3;
}

// ---------------------------------------------------------------------------
// ws layout (<=164 MB):
//  [0,4) qh  [4,8) ql  [8,12) kh  [12,16) kl   (oatt aliases [0,8) later)
//  [16,24) vs fp32   [24,28) vth  [28,32) vtl
//  [33,161) A        ([33,41) doubles as xh/xl before k_qk overwrites it)
//  [161,162.5) wth   [162.5,164) wtl
// ---------------------------------------------------------------------------
extern "C" void kernel_launch(void* const* d_in, const int* in_sizes, int n_in,
                              void* d_out, int out_size, void* d_ws, size_t ws_size,
                              hipStream_t stream)
{
  (void)in_sizes; (void)n_in; (void)out_size; (void)ws_size;
  const float* x  = (const float*)d_in[0];
  const float* wq = (const float*)d_in[1];
  const float* wk = (const float*)d_in[2];
  const float* wv = (const float*)d_in[3];
  const float* wo = (const float*)d_in[4];
  float* out = (float*)d_out;

  char* ws = (char*)d_ws;
  const size_t MB = 1024 * 1024;
  unsigned short* qh = (unsigned short*)(ws);
  unsigned short* ql = (unsigned short*)(ws + 4 * MB);
  unsigned short* kh = (unsigned short*)(ws + 8 * MB);
  unsigned short* kl = (unsigned short*)(ws + 12 * MB);
  float*          vs = (float*)(ws + 16 * MB);
  unsigned short* vth = (unsigned short*)(ws + 24 * MB);
  unsigned short* vtl = (unsigned short*)(ws + 28 * MB);
  float*          oatt = (float*)(ws);                    // aliases qh/ql (dead)
  float*          A  = (float*)(ws + 33 * MB);
  unsigned short* xh = (unsigned short*)(ws + 33 * MB);   // aliases A (dead by k_qk)
  unsigned short* xl = (unsigned short*)(ws + 37 * MB);
  unsigned short* wth = (unsigned short*)(ws + 161 * MB);
  unsigned short* wtl = (unsigned short*)(ws + 161 * MB + 1536 * 1024);

  hipLaunchKernelGGL(k_split_x, dim3(2048), dim3(256), 0, stream, x, xh, xl);
  hipLaunchKernelGGL(k_split_wt, dim3(8, 8, 3), dim3(256), 0, stream,
                     wq, wk, wv, wth, wtl);
  hipLaunchKernelGGL(k_proj_mfma, dim3(12, 32), dim3(256), 0, stream,
                     xh, xl, wth, wtl, qh, ql, kh, kl, vs);
  hipLaunchKernelGGL(k_vsplit, dim3(16, 32), dim3(256), 0, stream, vs, vth, vtl);
  hipLaunchKernelGGL(k_qk, dim3(1088), dim3(256), 0, stream, qh, ql, kh, kl, A);
  hipLaunchKernelGGL(k_scan, dim3(512), dim3(512), 0, stream, A);
  hipLaunchKernelGGL(k_pv, dim3(2048), dim3(64), 0, stream, A, vth, vtl, oatt);
  hipLaunchKernelGGL(k_oproj, dim3(64, 32), dim3(256), 0, stream,
                     oatt, wo, out);
}

// Round 9
// 243.271 us; speedup vs baseline: 1.4841x; 1.4841x over previous
//
#include <hip/hip_runtime.h>
#include <math.h>

#define BB    4
#define TT    1024
#define DD    512
#define NH    8
#define DH    64
#define BH    32          // BB*NH
#define INV_TAU 10.0f

typedef __attribute__((ext_vector_type(8))) short short8;
typedef __attribute__((ext_vector_type(4))) float f4;

__device__ inline unsigned short f2bf(float f) {
  unsigned u = __float_as_uint(f);
  u += 0x7FFFu + ((u >> 16) & 1u);        // round-to-nearest-even
  return (unsigned short)(u >> 16);
}
__device__ inline float bf2f(unsigned short h) {
  return __uint_as_float(((unsigned)h) << 16);
}

// ---------------------------------------------------------------------------
// P1: split x (fp32 [4096][512]) into bf16 hi/lo planes (same layout).
// ---------------------------------------------------------------------------
__global__ __launch_bounds__(256) void k_split_x(
    const float* __restrict__ x, unsigned short* __restrict__ xh,
    unsigned short* __restrict__ xl)
{
  const int i = (blockIdx.x * 256 + threadIdx.x) * 4;
  float4 v = *(const float4*)&x[i];
  ushort4 h, l;
  h.x = f2bf(v.x); l.x = f2bf(v.x - bf2f(h.x));
  h.y = f2bf(v.y); l.y = f2bf(v.y - bf2f(h.y));
  h.z = f2bf(v.z); l.z = f2bf(v.z - bf2f(h.z));
  h.w = f2bf(v.w); l.w = f2bf(v.w - bf2f(h.w));
  *(ushort4*)&xh[i] = h;
  *(ushort4*)&xl[i] = l;
}

// ---------------------------------------------------------------------------
// P2: transpose + split W -> wth/wtl [1536][512] bf16, k-contiguous rows.
// ---------------------------------------------------------------------------
__global__ __launch_bounds__(256) void k_split_wt(
    const float* __restrict__ wq, const float* __restrict__ wk,
    const float* __restrict__ wv, unsigned short* __restrict__ wth,
    unsigned short* __restrict__ wtl)
{
  __shared__ float Wf[64][65];
  const int ten = blockIdx.z;
  const float* W = (ten == 0) ? wq : ((ten == 1) ? wk : wv);
  const int n0 = blockIdx.x * 64, k0 = blockIdx.y * 64;
  const int tid = threadIdx.x;
#pragma unroll
  for (int p = 0; p < 4; ++p) {
    int kk = p * 16 + (tid >> 4);
    int nn = (tid & 15) * 4;
    float4 v = *(const float4*)&W[(size_t)(k0 + kk) * 512 + n0 + nn];
    Wf[kk][nn + 0] = v.x; Wf[kk][nn + 1] = v.y;
    Wf[kk][nn + 2] = v.z; Wf[kk][nn + 3] = v.w;
  }
  __syncthreads();
  const int n = tid >> 2, kq = tid & 3;
  size_t base = ((size_t)(ten * 512 + n0 + n)) * 512 + k0 + kq * 16;
#pragma unroll
  for (int jj = 0; jj < 4; ++jj) {
    ushort4 h, l;
    float f0 = Wf[kq * 16 + jj * 4 + 0][n];
    float f1 = Wf[kq * 16 + jj * 4 + 1][n];
    float f2 = Wf[kq * 16 + jj * 4 + 2][n];
    float f3 = Wf[kq * 16 + jj * 4 + 3][n];
    h.x = f2bf(f0); l.x = f2bf(f0 - bf2f(h.x));
    h.y = f2bf(f1); l.y = f2bf(f1 - bf2f(h.y));
    h.z = f2bf(f2); l.z = f2bf(f2 - bf2f(h.z));
    h.w = f2bf(f3); l.w = f2bf(f3 - bf2f(h.w));
    *(ushort4*)&wth[base + jj * 4] = h;
    *(ushort4*)&wtl[base + jj * 4] = l;
  }
}

// ---------------------------------------------------------------------------
// K1: QKV projection via bf16x3 MFMA + fused per-head softmax.
// ---------------------------------------------------------------------------
__global__ __launch_bounds__(256) void k_proj_mfma(
    const unsigned short* __restrict__ xh, const unsigned short* __restrict__ xl,
    const unsigned short* __restrict__ wth, const unsigned short* __restrict__ wtl,
    unsigned short* __restrict__ qh, unsigned short* __restrict__ ql,
    unsigned short* __restrict__ kh, unsigned short* __restrict__ kl,
    float* __restrict__ vs)
{
  __shared__ unsigned short Ah[128][40];
  __shared__ unsigned short Al[128][40];
  __shared__ unsigned short Bh[128][40];
  __shared__ unsigned short Bl[128][40];
  const int tid = threadIdx.x;
  const int n0g = blockIdx.x * 128;
  const int m0 = blockIdx.y * 128;
  const int w = tid >> 6, lane = tid & 63;
  const int mw = (w & 1) * 64, nw = (w >> 1) * 64;
  const int quad = lane >> 4, l16 = lane & 15;
  const int srow = tid >> 2;
  const int sk = (tid & 3) * 8;

  f4 acc[4][4] = {};

  for (int k0 = 0; k0 < DD; k0 += 32) {
    short8 a0 = *(const short8*)&xh[(size_t)(m0 + srow) * DD + k0 + sk];
    short8 a1 = *(const short8*)&xh[(size_t)(m0 + 64 + srow) * DD + k0 + sk];
    short8 a2 = *(const short8*)&xl[(size_t)(m0 + srow) * DD + k0 + sk];
    short8 a3 = *(const short8*)&xl[(size_t)(m0 + 64 + srow) * DD + k0 + sk];
    short8 b0 = *(const short8*)&wth[(size_t)(n0g + srow) * DD + k0 + sk];
    short8 b1 = *(const short8*)&wth[(size_t)(n0g + 64 + srow) * DD + k0 + sk];
    short8 b2 = *(const short8*)&wtl[(size_t)(n0g + srow) * DD + k0 + sk];
    short8 b3 = *(const short8*)&wtl[(size_t)(n0g + 64 + srow) * DD + k0 + sk];
    *(short8*)&Ah[srow][sk] = a0;  *(short8*)&Ah[64 + srow][sk] = a1;
    *(short8*)&Al[srow][sk] = a2;  *(short8*)&Al[64 + srow][sk] = a3;
    *(short8*)&Bh[srow][sk] = b0;  *(short8*)&Bh[64 + srow][sk] = b1;
    *(short8*)&Bl[srow][sk] = b2;  *(short8*)&Bl[64 + srow][sk] = b3;
    __syncthreads();

    short8 fbh[4], fbl[4];
#pragma unroll
    for (int nt = 0; nt < 4; ++nt) {
      fbh[nt] = *(const short8*)&Bh[nw + nt * 16 + l16][quad * 8];
      fbl[nt] = *(const short8*)&Bl[nw + nt * 16 + l16][quad * 8];
    }
#pragma unroll
    for (int mt = 0; mt < 4; ++mt) {
      short8 fah = *(const short8*)&Ah[mw + mt * 16 + l16][quad * 8];
      short8 fal = *(const short8*)&Al[mw + mt * 16 + l16][quad * 8];
#pragma unroll
      for (int nt = 0; nt < 4; ++nt) {
        acc[mt][nt] = __builtin_amdgcn_mfma_f32_16x16x32_bf16(fah, fbh[nt], acc[mt][nt], 0, 0, 0);
        acc[mt][nt] = __builtin_amdgcn_mfma_f32_16x16x32_bf16(fah, fbl[nt], acc[mt][nt], 0, 0, 0);
        acc[mt][nt] = __builtin_amdgcn_mfma_f32_16x16x32_bf16(fal, fbh[nt], acc[mt][nt], 0, 0, 0);
      }
    }
    __syncthreads();
  }

  const int tensor = n0g >> 9;
  const int ncol = (n0g & 511) + nw;
  const int h = ncol >> 6;
#pragma unroll
  for (int mt = 0; mt < 4; ++mt) {
#pragma unroll
    for (int r = 0; r < 4; ++r) {
      float v0 = acc[mt][0][r], v1 = acc[mt][1][r];
      float v2 = acc[mt][2][r], v3 = acc[mt][3][r];
      float mx = fmaxf(fmaxf(v0, v1), fmaxf(v2, v3));
#pragma unroll
      for (int msk = 1; msk <= 8; msk <<= 1) mx = fmaxf(mx, __shfl_xor(mx, msk, 64));
      float e0 = __expf((v0 - mx) * INV_TAU);
      float e1 = __expf((v1 - mx) * INV_TAU);
      float e2 = __expf((v2 - mx) * INV_TAU);
      float e3 = __expf((v3 - mx) * INV_TAU);
      float sm = e0 + e1 + e2 + e3;
#pragma unroll
      for (int msk = 1; msk <= 8; msk <<= 1) sm += __shfl_xor(sm, msk, 64);
      float inv = 1.0f / sm;
      int row = m0 + mw + mt * 16 + quad * 4 + r;
      int b = row >> 10, t = row & 1023;
      size_t base = (((size_t)b * NH + h) * TT + t) * DH;
      float e[4] = {e0 * inv, e1 * inv, e2 * inv, e3 * inv};
      if (tensor == 2) {
#pragma unroll
        for (int c = 0; c < 4; ++c) vs[base + l16 + c * 16] = e[c];
      } else {
        unsigned short* oh = tensor ? kh : qh;
        unsigned short* ol = tensor ? kl : ql;
#pragma unroll
        for (int c = 0; c < 4; ++c) {
          unsigned short hh = f2bf(e[c]);
          oh[base + l16 + c * 16] = hh;
          ol[base + l16 + c * 16] = f2bf(e[c] - bf2f(hh));
        }
      }
    }
  }
}

// ---------------------------------------------------------------------------
// P3: transpose + split V: vs [z][t][d] fp32 -> vth/vtl [z][d][t] bf16.
// ---------------------------------------------------------------------------
__global__ __launch_bounds__(256) void k_vsplit(
    const float* __restrict__ vs, unsigned short* __restrict__ vth,
    unsigned short* __restrict__ vtl)
{
  __shared__ float Vf[64][65];
  const int z = blockIdx.y, t0 = blockIdx.x * 64;
  const int tid = threadIdx.x;
#pragma unroll
  for (int it = 0; it < 4; ++it) {
    int tl = it * 16 + (tid >> 4);
    int d4 = (tid & 15) * 4;
    float4 v = *(const float4*)&vs[((size_t)z * TT + t0 + tl) * DH + d4];
    Vf[tl][d4 + 0] = v.x; Vf[tl][d4 + 1] = v.y;
    Vf[tl][d4 + 2] = v.z; Vf[tl][d4 + 3] = v.w;
  }
  __syncthreads();
#pragma unroll
  for (int it = 0; it < 8; ++it) {
    int d = it * 8 + (tid >> 5);
    int t = (tid & 31) * 2;
    float a0 = Vf[t][d], a1 = Vf[t + 1][d];
    unsigned short h0 = f2bf(a0), h1 = f2bf(a1);
    unsigned short l0 = f2bf(a0 - bf2f(h0)), l1 = f2bf(a1 - bf2f(h1));
    size_t o = ((size_t)z * DH + d) * TT + t0 + t;
    ushort2 hh; hh.x = h0; hh.y = h1;
    ushort2 ll; ll.x = l0; ll.y = l1;
    *(ushort2*)&vth[o] = hh;
    *(ushort2*)&vtl[o] = ll;
  }
}

// ---------------------------------------------------------------------------
// K2: scores via bf16x3 MFMA. One wave per lower-tri 64x64 tile.
// ---------------------------------------------------------------------------
__global__ __launch_bounds__(256) void k_qk(
    const unsigned short* __restrict__ qh, const unsigned short* __restrict__ ql,
    const unsigned short* __restrict__ kh, const unsigned short* __restrict__ kl,
    float* __restrict__ A)
{
  const int tid = threadIdx.x;
  const int gid = blockIdx.x * 4 + (tid >> 6);
  const int z = gid / 136;
  const int lx = gid - z * 136;
  int ti = (int)((sqrtf(8.0f * lx + 1.0f) - 1.0f) * 0.5f);
  while ((ti + 1) * (ti + 2) / 2 <= lx) ++ti;
  while (ti * (ti + 1) / 2 > lx) --ti;
  const int tj = lx - ti * (ti + 1) / 2;
  const int i0 = ti * 64, j0 = tj * 64;
  const int lane = tid & 63;
  const int quad = lane >> 4, l16 = lane & 15;
  const size_t zb = (size_t)z * TT * DH;

  short8 fbh[4][2], fbl[4][2];
#pragma unroll
  for (int nt = 0; nt < 4; ++nt)
#pragma unroll
    for (int ks = 0; ks < 2; ++ks) {
      size_t o = zb + (size_t)(j0 + nt * 16 + l16) * DH + ks * 32 + quad * 8;
      fbh[nt][ks] = *(const short8*)&kh[o];
      fbl[nt][ks] = *(const short8*)&kl[o];
    }

  f4 acc[4][4] = {};
#pragma unroll
  for (int mt = 0; mt < 4; ++mt) {
    short8 fah[2], fal[2];
#pragma unroll
    for (int ks = 0; ks < 2; ++ks) {
      size_t o = zb + (size_t)(i0 + mt * 16 + l16) * DH + ks * 32 + quad * 8;
      fah[ks] = *(const short8*)&qh[o];
      fal[ks] = *(const short8*)&ql[o];
    }
#pragma unroll
    for (int nt = 0; nt < 4; ++nt)
#pragma unroll
      for (int ks = 0; ks < 2; ++ks) {
        acc[mt][nt] = __builtin_amdgcn_mfma_f32_16x16x32_bf16(fah[ks], fbh[nt][ks], acc[mt][nt], 0, 0, 0);
        acc[mt][nt] = __builtin_amdgcn_mfma_f32_16x16x32_bf16(fah[ks], fbl[nt][ks], acc[mt][nt], 0, 0, 0);
        acc[mt][nt] = __builtin_amdgcn_mfma_f32_16x16x32_bf16(fal[ks], fbh[nt][ks], acc[mt][nt], 0, 0, 0);
      }
  }

  float* Ab = A + (size_t)z * TT * TT;
#pragma unroll
  for (int mt = 0; mt < 4; ++mt)
#pragma unroll
    for (int nt = 0; nt < 4; ++nt)
#pragma unroll
      for (int r = 0; r < 4; ++r)
        Ab[(size_t)(i0 + mt * 16 + quad * 4 + r) * TT + j0 + nt * 16 + l16] = acc[mt][nt][r];
}

// ---------------------------------------------------------------------------
// K3: diagonal run-length scan — R6's proven 3-pass body (20 VGPR, no
// spill), one group per block, 512 blocks for 2 blocks/CU (32 waves/CU).
// CU-load balancing: blocks b and b+256 land on the same CU under
// round-robin dispatch, so map p=blk>>5 -> xb with f(p)+f(p+8)=15:
// every CU gets 17 work-units. (Register-resident variants spill: R7/R8.)
// ---------------------------------------------------------------------------
__global__ __launch_bounds__(1024) void k_scan(float* __restrict__ A)
{
  __shared__ float Ssum[16][64];
  __shared__ float Gmax[16][64];
  const int blk = blockIdx.x;              // 0..511
  const int p = blk >> 5;                  // 0..15
  const int xb = (p < 8) ? p : (23 - p);   // complementary pairing across CUs
  const int z = blk & 31;
  const int lane = threadIdx.x & 63;
  const int w = threadIdx.x >> 6;          // chunk 0..15
  float* __restrict__ Ab = A + (size_t)z * TT * TT;
  const int dbase = xb * 64;
  const int d = dbase + lane;
  const int L = (TT - dbase) >> 4;         // 4..64 rows per chunk
  const int r0 = dbase + w * L;

  // Phase A: chunk sums
  float S = 0.0f;
#pragma unroll 8
  for (int t = 0; t < L; ++t) {
    int i = r0 + t;
    size_t idx = (i >= d) ? ((size_t)i * (TT + 1) - d) : 0;
    float s = Ab[idx];
    S += (i >= d) ? s : 0.0f;
  }
  Ssum[w][lane] = S;
  __syncthreads();

  float cs_in = 0.0f;
  for (int ww = 0; ww < w; ++ww) cs_in += Ssum[ww][lane];

  // Phase C: chunk g-max
  {
    float lcs = 0.0f, gm = 0.0f;
#pragma unroll 8
    for (int t = 0; t < L; ++t) {
      int i = r0 + t;
      size_t idx = (i >= d) ? ((size_t)i * (TT + 1) - d) : 0;
      float s0 = Ab[idx];
      float s = (i >= d) ? s0 : 0.0f;
      lcs += s;
      gm = fmaxf(gm, (cs_in + lcs) * (1.0f - s));
    }
    Gmax[w][lane] = gm;
  }
  __syncthreads();

  float m = 0.0f;
  for (int ww = 0; ww < w; ++ww) m = fmaxf(m, Gmax[ww][lane]);

  // Phase E: emit
  {
    float lcs = 0.0f;
#pragma unroll 8
    for (int t = 0; t < L; ++t) {
      int i = r0 + t;
      bool ok = (i >= d);
      size_t idx = ok ? ((size_t)i * (TT + 1) - d) : 0;
      float s0 = Ab[idx];
      float s = ok ? s0 : 0.0f;
      lcs += s;
      float cs = cs_in + lcs;
      m = fmaxf(m, cs * (1.0f - s));
      if (ok) Ab[idx] = cs - m;
    }
  }
}

// ---------------------------------------------------------------------------
// K4: fused flash-style softmax(P)·V. One wave per 16-row band (64-thr
// blocks, 2048 of them, heavy tiles first for dynamic balancing).
// ---------------------------------------------------------------------------
__global__ __launch_bounds__(64) void k_pv(
    const float* __restrict__ A, const unsigned short* __restrict__ vth,
    const unsigned short* __restrict__ vtl, float* __restrict__ oatt)
{
  const int lane = threadIdx.x;
  const int quad = lane >> 4, l16 = lane & 15;
  const int blk = blockIdx.x;              // 0..2047
  const int z = blk & 31;
  const int r = blk >> 5;                  // 0..63
  const int ti = 15 - (r >> 2);            // heavy (ti=15) first
  const int band = r & 3;
  const float* Az = A + (size_t)z * TT * TT;
  const unsigned short* vh = vth + (size_t)z * DH * TT;
  const unsigned short* vl = vtl + (size_t)z * DH * TT;

  const int i0 = ti * 64;
  const int irow = i0 + band * 16 + l16;   // this lane's P-row
  const float invi = 1.0f / (float)(irow + 1);
  f4 acc[4] = {};
  float m_old = -3e38f, l_run = 0.0f;

  for (int jt = 0; jt <= ti; ++jt) {
    float sc[16];
#pragma unroll
    for (int ks = 0; ks < 2; ++ks) {
      f4 s0 = *(const f4*)&Az[(size_t)irow * TT + jt * 64 + ks * 32 + quad * 8];
      f4 s1 = *(const f4*)&Az[(size_t)irow * TT + jt * 64 + ks * 32 + quad * 8 + 4];
#pragma unroll
      for (int u = 0; u < 4; ++u) { sc[ks * 8 + u] = s0[u]; sc[ks * 8 + 4 + u] = s1[u]; }
    }
#pragma unroll
    for (int u = 0; u < 16; ++u) {
      int j = jt * 64 + (u >> 3) * 32 + quad * 8 + (u & 7);
      float v = sc[u] + (float)j * invi;
      sc[u] = (j <= irow) ? v : -3e38f;
    }
    float mt_ = sc[0];
#pragma unroll
    for (int u = 1; u < 16; ++u) mt_ = fmaxf(mt_, sc[u]);
    mt_ = fmaxf(mt_, __shfl_xor(mt_, 16, 64));
    mt_ = fmaxf(mt_, __shfl_xor(mt_, 32, 64));
    float m_new = fmaxf(m_old, mt_);
    float alpha = __expf((m_old - m_new) * INV_TAU);
    unsigned short ph[16], pl[16];
    float ls = 0.0f;
#pragma unroll
    for (int u = 0; u < 16; ++u) {
      float pvv = __expf((sc[u] - m_new) * INV_TAU);
      unsigned short hh = f2bf(pvv);
      ph[u] = hh; pl[u] = f2bf(pvv - bf2f(hh));
      ls += pvv;
    }
    ls += __shfl_xor(ls, 16, 64);
    ls += __shfl_xor(ls, 32, 64);
    l_run = l_run * alpha + ls;
    m_old = m_new;
#pragma unroll
    for (int rr = 0; rr < 4; ++rr) {
      float ar = __shfl(alpha, quad * 4 + rr, 64);
#pragma unroll
      for (int nt = 0; nt < 4; ++nt) acc[nt][rr] *= ar;
    }
#pragma unroll
    for (int ks = 0; ks < 2; ++ks) {
      short8 pah, pal;
#pragma unroll
      for (int u = 0; u < 8; ++u) { pah[u] = (short)ph[ks * 8 + u]; pal[u] = (short)pl[ks * 8 + u]; }
#pragma unroll
      for (int nt = 0; nt < 4; ++nt) {
        size_t vo = (size_t)(nt * 16 + l16) * TT + jt * 64 + ks * 32 + quad * 8;
        short8 fvh = *(const short8*)&vh[vo];
        short8 fvl = *(const short8*)&vl[vo];
        acc[nt] = __builtin_amdgcn_mfma_f32_16x16x32_bf16(pah, fvh, acc[nt], 0, 0, 0);
        acc[nt] = __builtin_amdgcn_mfma_f32_16x16x32_bf16(pah, fvl, acc[nt], 0, 0, 0);
        acc[nt] = __builtin_amdgcn_mfma_f32_16x16x32_bf16(pal, fvh, acc[nt], 0, 0, 0);
      }
    }
  }
#pragma unroll
  for (int rr = 0; rr < 4; ++rr) {
    float lr = __shfl(l_run, quad * 4 + rr, 64);
    float inv = 1.0f / lr;
    int orow = i0 + band * 16 + quad * 4 + rr;
#pragma unroll
    for (int nt = 0; nt < 4; ++nt)
      oatt[((size_t)z * TT + orow) * DH + nt * 16 + l16] = acc[nt][rr] * inv;
  }
}

// ---------------------------------------------------------------------------
// K6: per-head output projection. 16 rows/block (W-tile amortized 4x,
// 4 independent FMA chains/thread — measured ~29 us win in R7).
// ---------------------------------------------------------------------------
__global__ __launch_bounds__(256) void k_oproj(
    const float* __restrict__ oatt, const float* __restrict__ wo,
    float* __restrict__ out)
{
  __shared__ float Wl[64][64];
  __shared__ float Ol[16][64];
  const int z = blockIdx.y;                // b*NH + h
  const int t0 = blockIdx.x * 16;
  const int b = z >> 3, h = z & 7;
  const int tid = threadIdx.x;
  const float* wb = wo + (size_t)h * 64 * 64;
#pragma unroll
  for (int u = 0; u < 4; ++u) {
    int q = tid + 256 * u;
    int dd = q >> 4, e4 = (q & 15) * 4;
    *(float4*)&Wl[dd][e4] = *(const float4*)&wb[(size_t)dd * 64 + e4];
  }
  {
    int rr = tid >> 4, d4 = (tid & 15) * 4;
    *(float4*)&Ol[rr][d4] = *(const float4*)&oatt[((size_t)z * TT + t0 + rr) * DH + d4];
  }
  __syncthreads();
  const int rg = tid >> 6, e = tid & 63;   // wave rg handles rows rg*4..rg*4+3
  float a0 = 0, a1 = 0, a2 = 0, a3 = 0;
#pragma unroll
  for (int dd = 0; dd < 64; ++dd) {
    float wv = Wl[dd][e];
    a0 += Ol[rg * 4 + 0][dd] * wv;
    a1 += Ol[rg * 4 + 1][dd] * wv;
    a2 += Ol[rg * 4 + 2][dd] * wv;
    a3 += Ol[rg * 4 + 3][dd] * wv;
  }
  size_t ob = ((size_t)b * TT + t0 + rg * 4) * DD + h * 64 + e;
  out[ob] = a0; out[ob + DD] = a1; out[ob + 2 * DD] = a2; out[ob + 3 * DD] = a3;
}

// ---------------------------------------------------------------------------
// ws layout (<=164 MB):
//  [0,4) qh  [4,8) ql  [8,12) kh  [12,16) kl   (oatt aliases [0,8) later)
//  [16,24) vs fp32   [24,28) vth  [28,32) vtl
//  [33,161) A        ([33,41) doubles as xh/xl before k_qk overwrites it)
//  [161,162.5) wth   [162.5,164) wtl
// ---------------------------------------------------------------------------
extern "C" void kernel_launch(void* const* d_in, const int* in_sizes, int n_in,
                              void* d_out, int out_size, void* d_ws, size_t ws_size,
                              hipStream_t stream)
{
  (void)in_sizes; (void)n_in; (void)out_size; (void)ws_size;
  const float* x  = (const float*)d_in[0];
  const float* wq = (const float*)d_in[1];
  const float* wk = (const float*)d_in[2];
  const float* wv = (const float*)d_in[3];
  const float* wo = (const float*)d_in[4];
  float* out = (float*)d_out;

  char* ws = (char*)d_ws;
  const size_t MB = 1024 * 1024;
  unsigned short* qh = (unsigned short*)(ws);
  unsigned short* ql = (unsigned short*)(ws + 4 * MB);
  unsigned short* kh = (unsigned short*)(ws + 8 * MB);
  unsigned short* kl = (unsigned short*)(ws + 12 * MB);
  float*          vs = (float*)(ws + 16 * MB);
  unsigned short* vth = (unsigned short*)(ws + 24 * MB);
  unsigned short* vtl = (unsigned short*)(ws + 28 * MB);
  float*          oatt = (float*)(ws);                    // aliases qh/ql (dead)
  float*          A  = (float*)(ws + 33 * MB);
  unsigned short* xh = (unsigned short*)(ws + 33 * MB);   // aliases A (dead by k_qk)
  unsigned short* xl = (unsigned short*)(ws + 37 * MB);
  unsigned short* wth = (unsigned short*)(ws + 161 * MB);
  unsigned short* wtl = (unsigned short*)(ws + 161 * MB + 1536 * 1024);

  hipLaunchKernelGGL(k_split_x, dim3(2048), dim3(256), 0, stream, x, xh, xl);
  hipLaunchKernelGGL(k_split_wt, dim3(8, 8, 3), dim3(256), 0, stream,
                     wq, wk, wv, wth, wtl);
  hipLaunchKernelGGL(k_proj_mfma, dim3(12, 32), dim3(256), 0, stream,
                     xh, xl, wth, wtl, qh, ql, kh, kl, vs);
  hipLaunchKernelGGL(k_vsplit, dim3(16, 32), dim3(256), 0, stream, vs, vth, vtl);
  hipLaunchKernelGGL(k_qk, dim3(1088), dim3(256), 0, stream, qh, ql, kh, kl, A);
  hipLaunchKernelGGL(k_scan, dim3(512), dim3(1024), 0, stream, A);
  hipLaunchKernelGGL(k_pv, dim3(2048), dim3(64), 0, stream, A, vth, vtl, oatt);
  hipLaunchKernelGGL(k_oproj, dim3(64, 32), dim3(256), 0, stream,
                     oatt, wo, out);
}

// Round 11
// 240.841 us; speedup vs baseline: 1.4990x; 1.0101x over previous
//
#include <hip/hip_runtime.h>
#include <math.h>

#define BB    4
#define TT    1024
#define DD    512
#define NH    8
#define DH    64
#define BH    32          // BB*NH
#define INV_TAU 10.0f

typedef __attribute__((ext_vector_type(8))) short short8;
typedef __attribute__((ext_vector_type(4))) float f4;

__device__ inline unsigned short f2bf(float f) {
  unsigned u = __float_as_uint(f);
  u += 0x7FFFu + ((u >> 16) & 1u);        // round-to-nearest-even
  return (unsigned short)(u >> 16);
}
__device__ inline float bf2f(unsigned short h) {
  return __uint_as_float(((unsigned)h) << 16);
}

// ---------------------------------------------------------------------------
// P1: split x (fp32 [4096][512]) into bf16 hi/lo planes (same layout).
// ---------------------------------------------------------------------------
__global__ __launch_bounds__(256) void k_split_x(
    const float* __restrict__ x, unsigned short* __restrict__ xh,
    unsigned short* __restrict__ xl)
{
  const int i = (blockIdx.x * 256 + threadIdx.x) * 4;
  float4 v = *(const float4*)&x[i];
  ushort4 h, l;
  h.x = f2bf(v.x); l.x = f2bf(v.x - bf2f(h.x));
  h.y = f2bf(v.y); l.y = f2bf(v.y - bf2f(h.y));
  h.z = f2bf(v.z); l.z = f2bf(v.z - bf2f(h.z));
  h.w = f2bf(v.w); l.w = f2bf(v.w - bf2f(h.w));
  *(ushort4*)&xh[i] = h;
  *(ushort4*)&xl[i] = l;
}

// ---------------------------------------------------------------------------
// P2: transpose + split W -> wth/wtl [1536][512] bf16, k-contiguous rows.
// ---------------------------------------------------------------------------
__global__ __launch_bounds__(256) void k_split_wt(
    const float* __restrict__ wq, const float* __restrict__ wk,
    const float* __restrict__ wv, unsigned short* __restrict__ wth,
    unsigned short* __restrict__ wtl)
{
  __shared__ float Wf[64][65];
  const int ten = blockIdx.z;
  const float* W = (ten == 0) ? wq : ((ten == 1) ? wk : wv);
  const int n0 = blockIdx.x * 64, k0 = blockIdx.y * 64;
  const int tid = threadIdx.x;
#pragma unroll
  for (int p = 0; p < 4; ++p) {
    int kk = p * 16 + (tid >> 4);
    int nn = (tid & 15) * 4;
    float4 v = *(const float4*)&W[(size_t)(k0 + kk) * 512 + n0 + nn];
    Wf[kk][nn + 0] = v.x; Wf[kk][nn + 1] = v.y;
    Wf[kk][nn + 2] = v.z; Wf[kk][nn + 3] = v.w;
  }
  __syncthreads();
  const int n = tid >> 2, kq = tid & 3;
  size_t base = ((size_t)(ten * 512 + n0 + n)) * 512 + k0 + kq * 16;
#pragma unroll
  for (int jj = 0; jj < 4; ++jj) {
    ushort4 h, l;
    float f0 = Wf[kq * 16 + jj * 4 + 0][n];
    float f1 = Wf[kq * 16 + jj * 4 + 1][n];
    float f2 = Wf[kq * 16 + jj * 4 + 2][n];
    float f3 = Wf[kq * 16 + jj * 4 + 3][n];
    h.x = f2bf(f0); l.x = f2bf(f0 - bf2f(h.x));
    h.y = f2bf(f1); l.y = f2bf(f1 - bf2f(h.y));
    h.z = f2bf(f2); l.z = f2bf(f2 - bf2f(h.z));
    h.w = f2bf(f3); l.w = f2bf(f3 - bf2f(h.w));
    *(ushort4*)&wth[base + jj * 4] = h;
    *(ushort4*)&wtl[base + jj * 4] = l;
  }
}

// ---------------------------------------------------------------------------
// K1: QKV projection via bf16x3 MFMA + fused per-head softmax.
// R10: 64(m)x128(n) tile, grid 12x64 = 768 blocks (3 blocks/CU, 12 waves/CU
// vs 1.5/6 for the old 128x128 — block-count quantization was the limiter).
// 4 waves as 2(m)x2(n); each wave 32x64 -> softmax stays wave-local.
// ---------------------------------------------------------------------------
__global__ __launch_bounds__(256) void k_proj_mfma(
    const unsigned short* __restrict__ xh, const unsigned short* __restrict__ xl,
    const unsigned short* __restrict__ wth, const unsigned short* __restrict__ wtl,
    unsigned short* __restrict__ qh, unsigned short* __restrict__ ql,
    unsigned short* __restrict__ kh, unsigned short* __restrict__ kl,
    float* __restrict__ vs)
{
  __shared__ unsigned short Ah[64][40];
  __shared__ unsigned short Al[64][40];
  __shared__ unsigned short Bh[128][40];
  __shared__ unsigned short Bl[128][40];
  const int tid = threadIdx.x;
  const int n0g = blockIdx.x * 128;        // 0..1408
  const int m0 = blockIdx.y * 64;          // 0..4032
  const int w = tid >> 6, lane = tid & 63;
  const int mw = (w & 1) * 32, nw = (w >> 1) * 64;
  const int quad = lane >> 4, l16 = lane & 15;
  const int srow = tid >> 2;               // 0..63
  const int sk = (tid & 3) * 8;            // 0,8,16,24

  f4 acc[2][4] = {};

  for (int k0 = 0; k0 < DD; k0 += 32) {
    short8 a0 = *(const short8*)&xh[(size_t)(m0 + srow) * DD + k0 + sk];
    short8 a1 = *(const short8*)&xl[(size_t)(m0 + srow) * DD + k0 + sk];
    short8 b0 = *(const short8*)&wth[(size_t)(n0g + srow) * DD + k0 + sk];
    short8 b1 = *(const short8*)&wth[(size_t)(n0g + 64 + srow) * DD + k0 + sk];
    short8 b2 = *(const short8*)&wtl[(size_t)(n0g + srow) * DD + k0 + sk];
    short8 b3 = *(const short8*)&wtl[(size_t)(n0g + 64 + srow) * DD + k0 + sk];
    *(short8*)&Ah[srow][sk] = a0;
    *(short8*)&Al[srow][sk] = a1;
    *(short8*)&Bh[srow][sk] = b0;  *(short8*)&Bh[64 + srow][sk] = b1;
    *(short8*)&Bl[srow][sk] = b2;  *(short8*)&Bl[64 + srow][sk] = b3;
    __syncthreads();

    short8 fbh[4], fbl[4];
#pragma unroll
    for (int nt = 0; nt < 4; ++nt) {
      fbh[nt] = *(const short8*)&Bh[nw + nt * 16 + l16][quad * 8];
      fbl[nt] = *(const short8*)&Bl[nw + nt * 16 + l16][quad * 8];
    }
#pragma unroll
    for (int mt = 0; mt < 2; ++mt) {
      short8 fah = *(const short8*)&Ah[mw + mt * 16 + l16][quad * 8];
      short8 fal = *(const short8*)&Al[mw + mt * 16 + l16][quad * 8];
#pragma unroll
      for (int nt = 0; nt < 4; ++nt) {
        acc[mt][nt] = __builtin_amdgcn_mfma_f32_16x16x32_bf16(fah, fbh[nt], acc[mt][nt], 0, 0, 0);
        acc[mt][nt] = __builtin_amdgcn_mfma_f32_16x16x32_bf16(fah, fbl[nt], acc[mt][nt], 0, 0, 0);
        acc[mt][nt] = __builtin_amdgcn_mfma_f32_16x16x32_bf16(fal, fbh[nt], acc[mt][nt], 0, 0, 0);
      }
    }
    __syncthreads();
  }

  const int tensor = n0g >> 9;
  const int ncol = (n0g & 511) + nw;
  const int h = ncol >> 6;
#pragma unroll
  for (int mt = 0; mt < 2; ++mt) {
#pragma unroll
    for (int r = 0; r < 4; ++r) {
      float v0 = acc[mt][0][r], v1 = acc[mt][1][r];
      float v2 = acc[mt][2][r], v3 = acc[mt][3][r];
      float mx = fmaxf(fmaxf(v0, v1), fmaxf(v2, v3));
#pragma unroll
      for (int msk = 1; msk <= 8; msk <<= 1) mx = fmaxf(mx, __shfl_xor(mx, msk, 64));
      float e0 = __expf((v0 - mx) * INV_TAU);
      float e1 = __expf((v1 - mx) * INV_TAU);
      float e2 = __expf((v2 - mx) * INV_TAU);
      float e3 = __expf((v3 - mx) * INV_TAU);
      float sm = e0 + e1 + e2 + e3;
#pragma unroll
      for (int msk = 1; msk <= 8; msk <<= 1) sm += __shfl_xor(sm, msk, 64);
      float inv = 1.0f / sm;
      int row = m0 + mw + mt * 16 + quad * 4 + r;
      int b = row >> 10, t = row & 1023;
      size_t base = (((size_t)b * NH + h) * TT + t) * DH;
      float e[4] = {e0 * inv, e1 * inv, e2 * inv, e3 * inv};
      if (tensor == 2) {
#pragma unroll
        for (int c = 0; c < 4; ++c) vs[base + l16 + c * 16] = e[c];
      } else {
        unsigned short* oh = tensor ? kh : qh;
        unsigned short* ol = tensor ? kl : ql;
#pragma unroll
        for (int c = 0; c < 4; ++c) {
          unsigned short hh = f2bf(e[c]);
          oh[base + l16 + c * 16] = hh;
          ol[base + l16 + c * 16] = f2bf(e[c] - bf2f(hh));
        }
      }
    }
  }
}

// ---------------------------------------------------------------------------
// P3: transpose + split V: vs [z][t][d] fp32 -> vth/vtl [z][d][t] bf16.
// ---------------------------------------------------------------------------
__global__ __launch_bounds__(256) void k_vsplit(
    const float* __restrict__ vs, unsigned short* __restrict__ vth,
    unsigned short* __restrict__ vtl)
{
  __shared__ float Vf[64][65];
  const int z = blockIdx.y, t0 = blockIdx.x * 64;
  const int tid = threadIdx.x;
#pragma unroll
  for (int it = 0; it < 4; ++it) {
    int tl = it * 16 + (tid >> 4);
    int d4 = (tid & 15) * 4;
    float4 v = *(const float4*)&vs[((size_t)z * TT + t0 + tl) * DH + d4];
    Vf[tl][d4 + 0] = v.x; Vf[tl][d4 + 1] = v.y;
    Vf[tl][d4 + 2] = v.z; Vf[tl][d4 + 3] = v.w;
  }
  __syncthreads();
#pragma unroll
  for (int it = 0; it < 8; ++it) {
    int d = it * 8 + (tid >> 5);
    int t = (tid & 31) * 2;
    float a0 = Vf[t][d], a1 = Vf[t + 1][d];
    unsigned short h0 = f2bf(a0), h1 = f2bf(a1);
    unsigned short l0 = f2bf(a0 - bf2f(h0)), l1 = f2bf(a1 - bf2f(h1));
    size_t o = ((size_t)z * DH + d) * TT + t0 + t;
    ushort2 hh; hh.x = h0; hh.y = h1;
    ushort2 ll; ll.x = l0; ll.y = l1;
    *(ushort2*)&vth[o] = hh;
    *(ushort2*)&vtl[o] = ll;
  }
}

// ---------------------------------------------------------------------------
// K2: scores via bf16x3 MFMA. One wave per lower-tri 64x64 tile.
// ---------------------------------------------------------------------------
__global__ __launch_bounds__(256) void k_qk(
    const unsigned short* __restrict__ qh, const unsigned short* __restrict__ ql,
    const unsigned short* __restrict__ kh, const unsigned short* __restrict__ kl,
    float* __restrict__ A)
{
  const int tid = threadIdx.x;
  const int gid = blockIdx.x * 4 + (tid >> 6);
  const int z = gid / 136;
  const int lx = gid - z * 136;
  int ti = (int)((sqrtf(8.0f * lx + 1.0f) - 1.0f) * 0.5f);
  while ((ti + 1) * (ti + 2) / 2 <= lx) ++ti;
  while (ti * (ti + 1) / 2 > lx) --ti;
  const int tj = lx - ti * (ti + 1) / 2;
  const int i0 = ti * 64, j0 = tj * 64;
  const int lane = tid & 63;
  const int quad = lane >> 4, l16 = lane & 15;
  const size_t zb = (size_t)z * TT * DH;

  short8 fbh[4][2], fbl[4][2];
#pragma unroll
  for (int nt = 0; nt < 4; ++nt)
#pragma unroll
    for (int ks = 0; ks < 2; ++ks) {
      size_t o = zb + (size_t)(j0 + nt * 16 + l16) * DH + ks * 32 + quad * 8;
      fbh[nt][ks] = *(const short8*)&kh[o];
      fbl[nt][ks] = *(const short8*)&kl[o];
    }

  f4 acc[4][4] = {};
#pragma unroll
  for (int mt = 0; mt < 4; ++mt) {
    short8 fah[2], fal[2];
#pragma unroll
    for (int ks = 0; ks < 2; ++ks) {
      size_t o = zb + (size_t)(i0 + mt * 16 + l16) * DH + ks * 32 + quad * 8;
      fah[ks] = *(const short8*)&qh[o];
      fal[ks] = *(const short8*)&ql[o];
    }
#pragma unroll
    for (int nt = 0; nt < 4; ++nt)
#pragma unroll
      for (int ks = 0; ks < 2; ++ks) {
        acc[mt][nt] = __builtin_amdgcn_mfma_f32_16x16x32_bf16(fah[ks], fbh[nt][ks], acc[mt][nt], 0, 0, 0);
        acc[mt][nt] = __builtin_amdgcn_mfma_f32_16x16x32_bf16(fah[ks], fbl[nt][ks], acc[mt][nt], 0, 0, 0);
        acc[mt][nt] = __builtin_amdgcn_mfma_f32_16x16x32_bf16(fal[ks], fbh[nt][ks], acc[mt][nt], 0, 0, 0);
      }
  }

  float* Ab = A + (size_t)z * TT * TT;
#pragma unroll
  for (int mt = 0; mt < 4; ++mt)
#pragma unroll
    for (int nt = 0; nt < 4; ++nt)
#pragma unroll
      for (int r = 0; r < 4; ++r)
        Ab[(size_t)(i0 + mt * 16 + quad * 4 + r) * TT + j0 + nt * 16 + l16] = acc[mt][nt][r];
}

// ---------------------------------------------------------------------------
// K3: diagonal run-length scan — R9 structure (proven 53.9 us, 16 VGPR).
// ---------------------------------------------------------------------------
__global__ __launch_bounds__(1024) void k_scan(float* __restrict__ A)
{
  __shared__ float Ssum[16][64];
  __shared__ float Gmax[16][64];
  const int blk = blockIdx.x;              // 0..511
  const int p = blk >> 5;                  // 0..15
  const int xb = (p < 8) ? p : (23 - p);   // complementary pairing across CUs
  const int z = blk & 31;
  const int lane = threadIdx.x & 63;
  const int w = threadIdx.x >> 6;          // chunk 0..15
  float* __restrict__ Ab = A + (size_t)z * TT * TT;
  const int dbase = xb * 64;
  const int d = dbase + lane;
  const int L = (TT - dbase) >> 4;         // 4..64 rows per chunk
  const int r0 = dbase + w * L;

  // Phase A: chunk sums
  float S = 0.0f;
#pragma unroll 8
  for (int t = 0; t < L; ++t) {
    int i = r0 + t;
    size_t idx = (i >= d) ? ((size_t)i * (TT + 1) - d) : 0;
    float s = Ab[idx];
    S += (i >= d) ? s : 0.0f;
  }
  Ssum[w][lane] = S;
  __syncthreads();

  float cs_in = 0.0f;
  for (int ww = 0; ww < w; ++ww) cs_in += Ssum[ww][lane];

  // Phase C: chunk g-max
  {
    float lcs = 0.0f, gm = 0.0f;
#pragma unroll 8
    for (int t = 0; t < L; ++t) {
      int i = r0 + t;
      size_t idx = (i >= d) ? ((size_t)i * (TT + 1) - d) : 0;
      float s0 = Ab[idx];
      float s = (i >= d) ? s0 : 0.0f;
      lcs += s;
      gm = fmaxf(gm, (cs_in + lcs) * (1.0f - s));
    }
    Gmax[w][lane] = gm;
  }
  __syncthreads();

  float m = 0.0f;
  for (int ww = 0; ww < w; ++ww) m = fmaxf(m, Gmax[ww][lane]);

  // Phase E: emit
  {
    float lcs = 0.0f;
#pragma unroll 8
    for (int t = 0; t < L; ++t) {
      int i = r0 + t;
      bool ok = (i >= d);
      size_t idx = ok ? ((size_t)i * (TT + 1) - d) : 0;
      float s0 = Ab[idx];
      float s = ok ? s0 : 0.0f;
      lcs += s;
      float cs = cs_in + lcs;
      m = fmaxf(m, cs * (1.0f - s));
      if (ok) Ab[idx] = cs - m;
    }
  }
}

// ---------------------------------------------------------------------------
// K4: fused flash-style softmax(P)·V. One wave per 16-row band.
// R10: jt loop split into unmasked body (jt<ti: every column valid, no
// cndmask) + masked diagonal tail; pos term = hoisted adds (no per-elem mul).
// ---------------------------------------------------------------------------
__global__ __launch_bounds__(64) void k_pv(
    const float* __restrict__ A, const unsigned short* __restrict__ vth,
    const unsigned short* __restrict__ vtl, float* __restrict__ oatt)
{
  const int lane = threadIdx.x;
  const int quad = lane >> 4, l16 = lane & 15;
  const int blk = blockIdx.x;              // 0..2047
  const int z = blk & 31;
  const int r = blk >> 5;                  // 0..63
  const int ti = 15 - (r >> 2);            // heavy (ti=15) first
  const int band = r & 3;
  const float* Az = A + (size_t)z * TT * TT;
  const unsigned short* vh = vth + (size_t)z * DH * TT;
  const unsigned short* vl = vtl + (size_t)z * DH * TT;

  const int i0 = ti * 64;
  const int irow = i0 + band * 16 + l16;   // this lane's P-row
  const float invi = 1.0f / (float)(irow + 1);
  f4 acc[4] = {};
  float m_old = -3e38f, l_run = 0.0f;

  // per-lane static position offsets: j = jt*64 + (u>>3)*32 + quad*8 + (u&7)
  float posu[16];
#pragma unroll
  for (int u = 0; u < 16; ++u)
    posu[u] = (float)((u >> 3) * 32 + quad * 8 + (u & 7)) * invi;
  float jtoff = 0.0f;
  const float jstep = 64.0f * invi;

#define PV_STEP(JT, MASKED)                                                   \
  {                                                                           \
    const int jt_ = (JT);                                                     \
    float sc[16];                                                             \
    _Pragma("unroll")                                                         \
    for (int ks = 0; ks < 2; ++ks) {                                          \
      f4 s0 = *(const f4*)&Az[(size_t)irow * TT + jt_ * 64 + ks * 32 + quad * 8];     \
      f4 s1 = *(const f4*)&Az[(size_t)irow * TT + jt_ * 64 + ks * 32 + quad * 8 + 4]; \
      _Pragma("unroll")                                                       \
      for (int u = 0; u < 4; ++u) { sc[ks * 8 + u] = s0[u]; sc[ks * 8 + 4 + u] = s1[u]; } \
    }                                                                         \
    _Pragma("unroll")                                                         \
    for (int u = 0; u < 16; ++u) {                                            \
      float v = sc[u] + (jtoff + posu[u]);                                    \
      if (MASKED) {                                                           \
        int j = jt_ * 64 + (u >> 3) * 32 + quad * 8 + (u & 7);                \
        sc[u] = (j <= irow) ? v : -3e38f;                                     \
      } else sc[u] = v;                                                       \
    }                                                                         \
    float mt_ = sc[0];                                                        \
    _Pragma("unroll")                                                         \
    for (int u = 1; u < 16; ++u) mt_ = fmaxf(mt_, sc[u]);                     \
    mt_ = fmaxf(mt_, __shfl_xor(mt_, 16, 64));                                \
    mt_ = fmaxf(mt_, __shfl_xor(mt_, 32, 64));                                \
    float m_new = fmaxf(m_old, mt_);                                          \
    float alpha = __expf((m_old - m_new) * INV_TAU);                          \
    unsigned short ph[16], pl[16];                                            \
    float ls = 0.0f;                                                          \
    _Pragma("unroll")                                                         \
    for (int u = 0; u < 16; ++u) {                                            \
      float pvv = __expf((sc[u] - m_new) * INV_TAU);                          \
      unsigned short hh = f2bf(pvv);                                          \
      ph[u] = hh; pl[u] = f2bf(pvv - bf2f(hh));                               \
      ls += pvv;                                                              \
    }                                                                         \
    ls += __shfl_xor(ls, 16, 64);                                             \
    ls += __shfl_xor(ls, 32, 64);                                             \
    l_run = l_run * alpha + ls;                                               \
    m_old = m_new;                                                            \
    _Pragma("unroll")                                                         \
    for (int rr = 0; rr < 4; ++rr) {                                          \
      float ar = __shfl(alpha, quad * 4 + rr, 64);                            \
      _Pragma("unroll")                                                       \
      for (int nt = 0; nt < 4; ++nt) acc[nt][rr] *= ar;                       \
    }                                                                         \
    _Pragma("unroll")                                                         \
    for (int ks = 0; ks < 2; ++ks) {                                          \
      short8 pah, pal;                                                        \
      _Pragma("unroll")                                                       \
      for (int u = 0; u < 8; ++u) { pah[u] = (short)ph[ks * 8 + u]; pal[u] = (short)pl[ks * 8 + u]; } \
      _Pragma("unroll")                                                       \
      for (int nt = 0; nt < 4; ++nt) {                                        \
        size_t vo = (size_t)(nt * 16 + l16) * TT + jt_ * 64 + ks * 32 + quad * 8; \
        short8 fvh = *(const short8*)&vh[vo];                                 \
        short8 fvl = *(const short8*)&vl[vo];                                 \
        acc[nt] = __builtin_amdgcn_mfma_f32_16x16x32_bf16(pah, fvh, acc[nt], 0, 0, 0); \
        acc[nt] = __builtin_amdgcn_mfma_f32_16x16x32_bf16(pah, fvl, acc[nt], 0, 0, 0); \
        acc[nt] = __builtin_amdgcn_mfma_f32_16x16x32_bf16(pal, fvh, acc[nt], 0, 0, 0); \
      }                                                                       \
    }                                                                         \
    jtoff += jstep;                                                           \
  }

  for (int jb = 0; jb < ti; ++jb) PV_STEP(jb, false);
  PV_STEP(ti, true);
#undef PV_STEP

#pragma unroll
  for (int rr = 0; rr < 4; ++rr) {
    float lr = __shfl(l_run, quad * 4 + rr, 64);
    float inv = 1.0f / lr;
    int orow = i0 + band * 16 + quad * 4 + rr;
#pragma unroll
    for (int nt = 0; nt < 4; ++nt)
      oatt[((size_t)z * TT + orow) * DH + nt * 16 + l16] = acc[nt][rr] * inv;
  }
}

// ---------------------------------------------------------------------------
// K6: per-head output projection. 16 rows/block.
// ---------------------------------------------------------------------------
__global__ __launch_bounds__(256) void k_oproj(
    const float* __restrict__ oatt, const float* __restrict__ wo,
    float* __restrict__ out)
{
  __shared__ float Wl[64][64];
  __shared__ float Ol[16][64];
  const int z = blockIdx.y;                // b*NH + h
  const int t0 = blockIdx.x * 16;
  const int b = z >> 3, h = z & 7;
  const int tid = threadIdx.x;
  const float* wb = wo + (size_t)h * 64 * 64;
#pragma unroll
  for (int u = 0; u < 4; ++u) {
    int q = tid + 256 * u;
    int dd = q >> 4, e4 = (q & 15) * 4;
    *(float4*)&Wl[dd][e4] = *(const float4*)&wb[(size_t)dd * 64 + e4];
  }
  {
    int rr = tid >> 4, d4 = (tid & 15) * 4;
    *(float4*)&Ol[rr][d4] = *(const float4*)&oatt[((size_t)z * TT + t0 + rr) * DH + d4];
  }
  __syncthreads();
  const int rg = tid >> 6, e = tid & 63;
  float a0 = 0, a1 = 0, a2 = 0, a3 = 0;
#pragma unroll
  for (int dd = 0; dd < 64; ++dd) {
    float wv = Wl[dd][e];
    a0 += Ol[rg * 4 + 0][dd] * wv;
    a1 += Ol[rg * 4 + 1][dd] * wv;
    a2 += Ol[rg * 4 + 2][dd] * wv;
    a3 += Ol[rg * 4 + 3][dd] * wv;
  }
  size_t ob = ((size_t)b * TT + t0 + rg * 4) * DD + h * 64 + e;
  out[ob] = a0; out[ob + DD] = a1; out[ob + 2 * DD] = a2; out[ob + 3 * DD] = a3;
}

// ---------------------------------------------------------------------------
// ws layout (<=164 MB):
//  [0,4) qh  [4,8) ql  [8,12) kh  [12,16) kl   (oatt aliases [0,8) later)
//  [16,24) vs fp32   [24,28) vth  [28,32) vtl
//  [33,161) A        ([33,41) doubles as xh/xl before k_qk overwrites it)
//  [161,162.5) wth   [162.5,164) wtl
// ---------------------------------------------------------------------------
extern "C" void kernel_launch(void* const* d_in, const int* in_sizes, int n_in,
                              void* d_out, int out_size, void* d_ws, size_t ws_size,
                              hipStream_t stream)
{
  (void)in_sizes; (void)n_in; (void)out_size; (void)ws_size;
  const float* x  = (const float*)d_in[0];
  const float* wq = (const float*)d_in[1];
  const float* wk = (const float*)d_in[2];
  const float* wv = (const float*)d_in[3];
  const float* wo = (const float*)d_in[4];
  float* out = (float*)d_out;

  char* ws = (char*)d_ws;
  const size_t MB = 1024 * 1024;
  unsigned short* qh = (unsigned short*)(ws);
  unsigned short* ql = (unsigned short*)(ws + 4 * MB);
  unsigned short* kh = (unsigned short*)(ws + 8 * MB);
  unsigned short* kl = (unsigned short*)(ws + 12 * MB);
  float*          vs = (float*)(ws + 16 * MB);
  unsigned short* vth = (unsigned short*)(ws + 24 * MB);
  unsigned short* vtl = (unsigned short*)(ws + 28 * MB);
  float*          oatt = (float*)(ws);                    // aliases qh/ql (dead)
  float*          A  = (float*)(ws + 33 * MB);
  unsigned short* xh = (unsigned short*)(ws + 33 * MB);   // aliases A (dead by k_qk)
  unsigned short* xl = (unsigned short*)(ws + 37 * MB);
  unsigned short* wth = (unsigned short*)(ws + 161 * MB);
  unsigned short* wtl = (unsigned short*)(ws + 161 * MB + 1536 * 1024);

  hipLaunchKernelGGL(k_split_x, dim3(2048), dim3(256), 0, stream, x, xh, xl);
  hipLaunchKernelGGL(k_split_wt, dim3(8, 8, 3), dim3(256), 0, stream,
                     wq, wk, wv, wth, wtl);
  hipLaunchKernelGGL(k_proj_mfma, dim3(12, 64), dim3(256), 0, stream,
                     xh, xl, wth, wtl, qh, ql, kh, kl, vs);
  hipLaunchKernelGGL(k_vsplit, dim3(16, 32), dim3(256), 0, stream, vs, vth, vtl);
  hipLaunchKernelGGL(k_qk, dim3(1088), dim3(256), 0, stream, qh, ql, kh, kl, A);
  hipLaunchKernelGGL(k_scan, dim3(512), dim3(1024), 0, stream, A);
  hipLaunchKernelGGL(k_pv, dim3(2048), dim3(64), 0, stream, A, vth, vtl, oatt);
  hipLaunchKernelGGL(k_oproj, dim3(64, 32), dim3(256), 0, stream,
                     oatt, wo, out);
}

// Round 12
// 219.968 us; speedup vs baseline: 1.6413x; 1.0949x over previous
//
#include <hip/hip_runtime.h>
#include <math.h>

#define BB    4
#define TT    1024
#define DD    512
#define NH    8
#define DH    64
#define BH    32          // BB*NH
#define INV_TAU 10.0f

typedef __attribute__((ext_vector_type(8))) short short8;
typedef __attribute__((ext_vector_type(4))) float f4;
typedef __attribute__((ext_vector_type(8))) _Float16 half8;

__device__ inline unsigned short f2bf(float f) {
  unsigned u = __float_as_uint(f);
  u += 0x7FFFu + ((u >> 16) & 1u);        // round-to-nearest-even
  return (unsigned short)(u >> 16);
}
__device__ inline float bf2f(unsigned short h) {
  return __uint_as_float(((unsigned)h) << 16);
}

// ---------------------------------------------------------------------------
// K0 "prep": merged split_x (blocks 0..2047) + split_wt (blocks 2048..2239).
// split_x: x fp32 -> bf16 hi/lo planes. split_wt: W transpose+split,
// k-contiguous rows.
// ---------------------------------------------------------------------------
__global__ __launch_bounds__(256) void k_prep(
    const float* __restrict__ x, const float* __restrict__ wq,
    const float* __restrict__ wk, const float* __restrict__ wv,
    unsigned short* __restrict__ xh, unsigned short* __restrict__ xl,
    unsigned short* __restrict__ wth, unsigned short* __restrict__ wtl)
{
  __shared__ float Wf[64][65];
  const int blk = blockIdx.x;
  const int tid = threadIdx.x;
  if (blk < 2048) {
    const int i = (blk * 256 + tid) * 4;
    float4 v = *(const float4*)&x[i];
    ushort4 h, l;
    h.x = f2bf(v.x); l.x = f2bf(v.x - bf2f(h.x));
    h.y = f2bf(v.y); l.y = f2bf(v.y - bf2f(h.y));
    h.z = f2bf(v.z); l.z = f2bf(v.z - bf2f(h.z));
    h.w = f2bf(v.w); l.w = f2bf(v.w - bf2f(h.w));
    *(ushort4*)&xh[i] = h;
    *(ushort4*)&xl[i] = l;
    return;
  }
  const int b = blk - 2048;                // 0..191
  const int ten = b >> 6;                  // 0..2
  const int r = b & 63;
  const int n0 = (r & 7) * 64, k0 = (r >> 3) * 64;
  const float* W = (ten == 0) ? wq : ((ten == 1) ? wk : wv);
#pragma unroll
  for (int p = 0; p < 4; ++p) {
    int kk = p * 16 + (tid >> 4);
    int nn = (tid & 15) * 4;
    float4 v = *(const float4*)&W[(size_t)(k0 + kk) * 512 + n0 + nn];
    Wf[kk][nn + 0] = v.x; Wf[kk][nn + 1] = v.y;
    Wf[kk][nn + 2] = v.z; Wf[kk][nn + 3] = v.w;
  }
  __syncthreads();
  const int n = tid >> 2, kq = tid & 3;
  size_t base = ((size_t)(ten * 512 + n0 + n)) * 512 + k0 + kq * 16;
#pragma unroll
  for (int jj = 0; jj < 4; ++jj) {
    ushort4 h, l;
    float f0 = Wf[kq * 16 + jj * 4 + 0][n];
    float f1 = Wf[kq * 16 + jj * 4 + 1][n];
    float f2 = Wf[kq * 16 + jj * 4 + 2][n];
    float f3 = Wf[kq * 16 + jj * 4 + 3][n];
    h.x = f2bf(f0); l.x = f2bf(f0 - bf2f(h.x));
    h.y = f2bf(f1); l.y = f2bf(f1 - bf2f(h.y));
    h.z = f2bf(f2); l.z = f2bf(f2 - bf2f(h.z));
    h.w = f2bf(f3); l.w = f2bf(f3 - bf2f(h.w));
    *(ushort4*)&wth[base + jj * 4] = h;
    *(ushort4*)&wtl[base + jj * 4] = l;
  }
}

// ---------------------------------------------------------------------------
// K1: QKV projection via bf16x3 MFMA + fused per-head softmax.
// 64(m)x128(n) tile, grid 12x64 = 768 blocks; waves 2(m)x2(n), 32x64 each.
// ---------------------------------------------------------------------------
__global__ __launch_bounds__(256) void k_proj_mfma(
    const unsigned short* __restrict__ xh, const unsigned short* __restrict__ xl,
    const unsigned short* __restrict__ wth, const unsigned short* __restrict__ wtl,
    unsigned short* __restrict__ qh, unsigned short* __restrict__ ql,
    unsigned short* __restrict__ kh, unsigned short* __restrict__ kl,
    float* __restrict__ vs)
{
  __shared__ unsigned short Ah[64][40];
  __shared__ unsigned short Al[64][40];
  __shared__ unsigned short Bh[128][40];
  __shared__ unsigned short Bl[128][40];
  const int tid = threadIdx.x;
  const int n0g = blockIdx.x * 128;        // 0..1408
  const int m0 = blockIdx.y * 64;          // 0..4032
  const int w = tid >> 6, lane = tid & 63;
  const int mw = (w & 1) * 32, nw = (w >> 1) * 64;
  const int quad = lane >> 4, l16 = lane & 15;
  const int srow = tid >> 2;               // 0..63
  const int sk = (tid & 3) * 8;            // 0,8,16,24

  f4 acc[2][4] = {};

  for (int k0 = 0; k0 < DD; k0 += 32) {
    short8 a0 = *(const short8*)&xh[(size_t)(m0 + srow) * DD + k0 + sk];
    short8 a1 = *(const short8*)&xl[(size_t)(m0 + srow) * DD + k0 + sk];
    short8 b0 = *(const short8*)&wth[(size_t)(n0g + srow) * DD + k0 + sk];
    short8 b1 = *(const short8*)&wth[(size_t)(n0g + 64 + srow) * DD + k0 + sk];
    short8 b2 = *(const short8*)&wtl[(size_t)(n0g + srow) * DD + k0 + sk];
    short8 b3 = *(const short8*)&wtl[(size_t)(n0g + 64 + srow) * DD + k0 + sk];
    *(short8*)&Ah[srow][sk] = a0;
    *(short8*)&Al[srow][sk] = a1;
    *(short8*)&Bh[srow][sk] = b0;  *(short8*)&Bh[64 + srow][sk] = b1;
    *(short8*)&Bl[srow][sk] = b2;  *(short8*)&Bl[64 + srow][sk] = b3;
    __syncthreads();

    short8 fbh[4], fbl[4];
#pragma unroll
    for (int nt = 0; nt < 4; ++nt) {
      fbh[nt] = *(const short8*)&Bh[nw + nt * 16 + l16][quad * 8];
      fbl[nt] = *(const short8*)&Bl[nw + nt * 16 + l16][quad * 8];
    }
#pragma unroll
    for (int mt = 0; mt < 2; ++mt) {
      short8 fah = *(const short8*)&Ah[mw + mt * 16 + l16][quad * 8];
      short8 fal = *(const short8*)&Al[mw + mt * 16 + l16][quad * 8];
#pragma unroll
      for (int nt = 0; nt < 4; ++nt) {
        acc[mt][nt] = __builtin_amdgcn_mfma_f32_16x16x32_bf16(fah, fbh[nt], acc[mt][nt], 0, 0, 0);
        acc[mt][nt] = __builtin_amdgcn_mfma_f32_16x16x32_bf16(fah, fbl[nt], acc[mt][nt], 0, 0, 0);
        acc[mt][nt] = __builtin_amdgcn_mfma_f32_16x16x32_bf16(fal, fbh[nt], acc[mt][nt], 0, 0, 0);
      }
    }
    __syncthreads();
  }

  const int tensor = n0g >> 9;
  const int ncol = (n0g & 511) + nw;
  const int h = ncol >> 6;
#pragma unroll
  for (int mt = 0; mt < 2; ++mt) {
#pragma unroll
    for (int r = 0; r < 4; ++r) {
      float v0 = acc[mt][0][r], v1 = acc[mt][1][r];
      float v2 = acc[mt][2][r], v3 = acc[mt][3][r];
      float mx = fmaxf(fmaxf(v0, v1), fmaxf(v2, v3));
#pragma unroll
      for (int msk = 1; msk <= 8; msk <<= 1) mx = fmaxf(mx, __shfl_xor(mx, msk, 64));
      float e0 = __expf((v0 - mx) * INV_TAU);
      float e1 = __expf((v1 - mx) * INV_TAU);
      float e2 = __expf((v2 - mx) * INV_TAU);
      float e3 = __expf((v3 - mx) * INV_TAU);
      float sm = e0 + e1 + e2 + e3;
#pragma unroll
      for (int msk = 1; msk <= 8; msk <<= 1) sm += __shfl_xor(sm, msk, 64);
      float inv = 1.0f / sm;
      int row = m0 + mw + mt * 16 + quad * 4 + r;
      int b = row >> 10, t = row & 1023;
      size_t base = (((size_t)b * NH + h) * TT + t) * DH;
      float e[4] = {e0 * inv, e1 * inv, e2 * inv, e3 * inv};
      if (tensor == 2) {
#pragma unroll
        for (int c = 0; c < 4; ++c) vs[base + l16 + c * 16] = e[c];
      } else {
        unsigned short* oh = tensor ? kh : qh;
        unsigned short* ol = tensor ? kl : ql;
#pragma unroll
        for (int c = 0; c < 4; ++c) {
          unsigned short hh = f2bf(e[c]);
          oh[base + l16 + c * 16] = hh;
          ol[base + l16 + c * 16] = f2bf(e[c] - bf2f(hh));
        }
      }
    }
  }
}

// ---------------------------------------------------------------------------
// K2 "qkv": merged qk (blocks 0..1087) + vsplit (blocks 1088..1599).
// qk: scores via bf16x3 MFMA, one wave per lower-tri 64x64 tile, A in fp16.
// vsplit: vs [z][t][d] fp32 -> vth/vtl [z][d][t] bf16.
// ---------------------------------------------------------------------------
__global__ __launch_bounds__(256) void k_qkv(
    const unsigned short* __restrict__ qh, const unsigned short* __restrict__ ql,
    const unsigned short* __restrict__ kh, const unsigned short* __restrict__ kl,
    _Float16* __restrict__ A, const float* __restrict__ vs,
    unsigned short* __restrict__ vth, unsigned short* __restrict__ vtl)
{
  __shared__ float Vf[64][65];
  const int tid = threadIdx.x;
  if (blockIdx.x >= 1088) {
    // ---- vsplit half ----
    const int b = blockIdx.x - 1088;       // 0..511
    const int z = b & 31, t0 = (b >> 5) * 64;
#pragma unroll
    for (int it = 0; it < 4; ++it) {
      int tl = it * 16 + (tid >> 4);
      int d4 = (tid & 15) * 4;
      float4 v = *(const float4*)&vs[((size_t)z * TT + t0 + tl) * DH + d4];
      Vf[tl][d4 + 0] = v.x; Vf[tl][d4 + 1] = v.y;
      Vf[tl][d4 + 2] = v.z; Vf[tl][d4 + 3] = v.w;
    }
    __syncthreads();
#pragma unroll
    for (int it = 0; it < 8; ++it) {
      int d = it * 8 + (tid >> 5);
      int t = (tid & 31) * 2;
      float a0 = Vf[t][d], a1 = Vf[t + 1][d];
      unsigned short h0 = f2bf(a0), h1 = f2bf(a1);
      unsigned short l0 = f2bf(a0 - bf2f(h0)), l1 = f2bf(a1 - bf2f(h1));
      size_t o = ((size_t)z * DH + d) * TT + t0 + t;
      ushort2 hh; hh.x = h0; hh.y = h1;
      ushort2 ll; ll.x = l0; ll.y = l1;
      *(ushort2*)&vth[o] = hh;
      *(ushort2*)&vtl[o] = ll;
    }
    return;
  }
  // ---- qk half ----
  const int gid = blockIdx.x * 4 + (tid >> 6);
  const int z = gid / 136;
  const int lx = gid - z * 136;
  int ti = (int)((sqrtf(8.0f * lx + 1.0f) - 1.0f) * 0.5f);
  while ((ti + 1) * (ti + 2) / 2 <= lx) ++ti;
  while (ti * (ti + 1) / 2 > lx) --ti;
  const int tj = lx - ti * (ti + 1) / 2;
  const int i0 = ti * 64, j0 = tj * 64;
  const int lane = tid & 63;
  const int quad = lane >> 4, l16 = lane & 15;
  const size_t zb = (size_t)z * TT * DH;

  short8 fbh[4][2], fbl[4][2];
#pragma unroll
  for (int nt = 0; nt < 4; ++nt)
#pragma unroll
    for (int ks = 0; ks < 2; ++ks) {
      size_t o = zb + (size_t)(j0 + nt * 16 + l16) * DH + ks * 32 + quad * 8;
      fbh[nt][ks] = *(const short8*)&kh[o];
      fbl[nt][ks] = *(const short8*)&kl[o];
    }

  f4 acc[4][4] = {};
#pragma unroll
  for (int mt = 0; mt < 4; ++mt) {
    short8 fah[2], fal[2];
#pragma unroll
    for (int ks = 0; ks < 2; ++ks) {
      size_t o = zb + (size_t)(i0 + mt * 16 + l16) * DH + ks * 32 + quad * 8;
      fah[ks] = *(const short8*)&qh[o];
      fal[ks] = *(const short8*)&ql[o];
    }
#pragma unroll
    for (int nt = 0; nt < 4; ++nt)
#pragma unroll
      for (int ks = 0; ks < 2; ++ks) {
        acc[mt][nt] = __builtin_amdgcn_mfma_f32_16x16x32_bf16(fah[ks], fbh[nt][ks], acc[mt][nt], 0, 0, 0);
        acc[mt][nt] = __builtin_amdgcn_mfma_f32_16x16x32_bf16(fah[ks], fbl[nt][ks], acc[mt][nt], 0, 0, 0);
        acc[mt][nt] = __builtin_amdgcn_mfma_f32_16x16x32_bf16(fal[ks], fbh[nt][ks], acc[mt][nt], 0, 0, 0);
      }
  }

  _Float16* Ab = A + (size_t)z * TT * TT;
#pragma unroll
  for (int mt = 0; mt < 4; ++mt)
#pragma unroll
    for (int nt = 0; nt < 4; ++nt)
#pragma unroll
      for (int r = 0; r < 4; ++r)
        Ab[(size_t)(i0 + mt * 16 + quad * 4 + r) * TT + j0 + nt * 16 + l16] =
            (_Float16)acc[mt][nt][r];
}

// ---------------------------------------------------------------------------
// K3: diagonal run-length scan — R9 3-pass structure (no-spill), fp16 I/O
// with fp32 in-kernel math.
// ---------------------------------------------------------------------------
__global__ __launch_bounds__(1024) void k_scan(_Float16* __restrict__ A)
{
  __shared__ float Ssum[16][64];
  __shared__ float Gmax[16][64];
  const int blk = blockIdx.x;              // 0..511
  const int p = blk >> 5;                  // 0..15
  const int xb = (p < 8) ? p : (23 - p);   // complementary pairing across CUs
  const int z = blk & 31;
  const int lane = threadIdx.x & 63;
  const int w = threadIdx.x >> 6;          // chunk 0..15
  _Float16* __restrict__ Ab = A + (size_t)z * TT * TT;
  const int dbase = xb * 64;
  const int d = dbase + lane;
  const int L = (TT - dbase) >> 4;         // 4..64 rows per chunk
  const int r0 = dbase + w * L;

  // Phase A: chunk sums
  float S = 0.0f;
#pragma unroll 8
  for (int t = 0; t < L; ++t) {
    int i = r0 + t;
    size_t idx = (i >= d) ? ((size_t)i * (TT + 1) - d) : 0;
    float s = (float)Ab[idx];
    S += (i >= d) ? s : 0.0f;
  }
  Ssum[w][lane] = S;
  __syncthreads();

  float cs_in = 0.0f;
  for (int ww = 0; ww < w; ++ww) cs_in += Ssum[ww][lane];

  // Phase C: chunk g-max
  {
    float lcs = 0.0f, gm = 0.0f;
#pragma unroll 8
    for (int t = 0; t < L; ++t) {
      int i = r0 + t;
      size_t idx = (i >= d) ? ((size_t)i * (TT + 1) - d) : 0;
      float s0 = (float)Ab[idx];
      float s = (i >= d) ? s0 : 0.0f;
      lcs += s;
      gm = fmaxf(gm, (cs_in + lcs) * (1.0f - s));
    }
    Gmax[w][lane] = gm;
  }
  __syncthreads();

  float m = 0.0f;
  for (int ww = 0; ww < w; ++ww) m = fmaxf(m, Gmax[ww][lane]);

  // Phase E: emit
  {
    float lcs = 0.0f;
#pragma unroll 8
    for (int t = 0; t < L; ++t) {
      int i = r0 + t;
      bool ok = (i >= d);
      size_t idx = ok ? ((size_t)i * (TT + 1) - d) : 0;
      float s0 = (float)Ab[idx];
      float s = ok ? s0 : 0.0f;
      lcs += s;
      float cs = cs_in + lcs;
      m = fmaxf(m, cs * (1.0f - s));
      if (ok) Ab[idx] = (_Float16)(cs - m);
    }
  }
}

// ---------------------------------------------------------------------------
// K4: fused flash-style softmax(P)·V, fp16 A input. One wave per 16-row
// band; unmasked body + masked diagonal tail; hoisted pos-adds.
// ---------------------------------------------------------------------------
__global__ __launch_bounds__(64) void k_pv(
    const _Float16* __restrict__ A, const unsigned short* __restrict__ vth,
    const unsigned short* __restrict__ vtl, float* __restrict__ oatt)
{
  const int lane = threadIdx.x;
  const int quad = lane >> 4, l16 = lane & 15;
  const int blk = blockIdx.x;              // 0..2047
  const int z = blk & 31;
  const int r = blk >> 5;                  // 0..63
  const int ti = 15 - (r >> 2);            // heavy (ti=15) first
  const int band = r & 3;
  const _Float16* Az = A + (size_t)z * TT * TT;
  const unsigned short* vh = vth + (size_t)z * DH * TT;
  const unsigned short* vl = vtl + (size_t)z * DH * TT;

  const int i0 = ti * 64;
  const int irow = i0 + band * 16 + l16;   // this lane's P-row
  const float invi = 1.0f / (float)(irow + 1);
  f4 acc[4] = {};
  float m_old = -3e38f, l_run = 0.0f;

  float posu[16];
#pragma unroll
  for (int u = 0; u < 16; ++u)
    posu[u] = (float)((u >> 3) * 32 + quad * 8 + (u & 7)) * invi;
  float jtoff = 0.0f;
  const float jstep = 64.0f * invi;

#define PV_STEP(JT, MASKED)                                                   \
  {                                                                           \
    const int jt_ = (JT);                                                     \
    float sc[16];                                                             \
    _Pragma("unroll")                                                         \
    for (int ks = 0; ks < 2; ++ks) {                                          \
      half8 hv = *(const half8*)&Az[(size_t)irow * TT + jt_ * 64 + ks * 32 + quad * 8]; \
      _Pragma("unroll")                                                       \
      for (int u = 0; u < 8; ++u) sc[ks * 8 + u] = (float)hv[u];              \
    }                                                                         \
    _Pragma("unroll")                                                         \
    for (int u = 0; u < 16; ++u) {                                            \
      float v = sc[u] + (jtoff + posu[u]);                                    \
      if (MASKED) {                                                           \
        int j = jt_ * 64 + (u >> 3) * 32 + quad * 8 + (u & 7);                \
        sc[u] = (j <= irow) ? v : -3e38f;                                     \
      } else sc[u] = v;                                                       \
    }                                                                         \
    float mt_ = sc[0];                                                        \
    _Pragma("unroll")                                                         \
    for (int u = 1; u < 16; ++u) mt_ = fmaxf(mt_, sc[u]);                     \
    mt_ = fmaxf(mt_, __shfl_xor(mt_, 16, 64));                                \
    mt_ = fmaxf(mt_, __shfl_xor(mt_, 32, 64));                                \
    float m_new = fmaxf(m_old, mt_);                                          \
    float alpha = __expf((m_old - m_new) * INV_TAU);                          \
    unsigned short ph[16], pl[16];                                            \
    float ls = 0.0f;                                                          \
    _Pragma("unroll")                                                         \
    for (int u = 0; u < 16; ++u) {                                            \
      float pvv = __expf((sc[u] - m_new) * INV_TAU);                          \
      unsigned short hh = f2bf(pvv);                                          \
      ph[u] = hh; pl[u] = f2bf(pvv - bf2f(hh));                               \
      ls += pvv;                                                              \
    }                                                                         \
    ls += __shfl_xor(ls, 16, 64);                                             \
    ls += __shfl_xor(ls, 32, 64);                                             \
    l_run = l_run * alpha + ls;                                               \
    m_old = m_new;                                                            \
    _Pragma("unroll")                                                         \
    for (int rr = 0; rr < 4; ++rr) {                                          \
      float ar = __shfl(alpha, quad * 4 + rr, 64);                            \
      _Pragma("unroll")                                                       \
      for (int nt = 0; nt < 4; ++nt) acc[nt][rr] *= ar;                       \
    }                                                                         \
    _Pragma("unroll")                                                         \
    for (int ks = 0; ks < 2; ++ks) {                                          \
      short8 pah, pal;                                                        \
      _Pragma("unroll")                                                       \
      for (int u = 0; u < 8; ++u) { pah[u] = (short)ph[ks * 8 + u]; pal[u] = (short)pl[ks * 8 + u]; } \
      _Pragma("unroll")                                                       \
      for (int nt = 0; nt < 4; ++nt) {                                        \
        size_t vo = (size_t)(nt * 16 + l16) * TT + jt_ * 64 + ks * 32 + quad * 8; \
        short8 fvh = *(const short8*)&vh[vo];                                 \
        short8 fvl = *(const short8*)&vl[vo];                                 \
        acc[nt] = __builtin_amdgcn_mfma_f32_16x16x32_bf16(pah, fvh, acc[nt], 0, 0, 0); \
        acc[nt] = __builtin_amdgcn_mfma_f32_16x16x32_bf16(pah, fvl, acc[nt], 0, 0, 0); \
        acc[nt] = __builtin_amdgcn_mfma_f32_16x16x32_bf16(pal, fvh, acc[nt], 0, 0, 0); \
      }                                                                       \
    }                                                                         \
    jtoff += jstep;                                                           \
  }

  for (int jb = 0; jb < ti; ++jb) PV_STEP(jb, false);
  PV_STEP(ti, true);
#undef PV_STEP

#pragma unroll
  for (int rr = 0; rr < 4; ++rr) {
    float lr = __shfl(l_run, quad * 4 + rr, 64);
    float inv = 1.0f / lr;
    int orow = i0 + band * 16 + quad * 4 + rr;
#pragma unroll
    for (int nt = 0; nt < 4; ++nt)
      oatt[((size_t)z * TT + orow) * DH + nt * 16 + l16] = acc[nt][rr] * inv;
  }
}

// ---------------------------------------------------------------------------
// K6: per-head output projection. 16 rows/block.
// ---------------------------------------------------------------------------
__global__ __launch_bounds__(256) void k_oproj(
    const float* __restrict__ oatt, const float* __restrict__ wo,
    float* __restrict__ out)
{
  __shared__ float Wl[64][64];
  __shared__ float Ol[16][64];
  const int z = blockIdx.y;                // b*NH + h
  const int t0 = blockIdx.x * 16;
  const int b = z >> 3, h = z & 7;
  const int tid = threadIdx.x;
  const float* wb = wo + (size_t)h * 64 * 64;
#pragma unroll
  for (int u = 0; u < 4; ++u) {
    int q = tid + 256 * u;
    int dd = q >> 4, e4 = (q & 15) * 4;
    *(float4*)&Wl[dd][e4] = *(const float4*)&wb[(size_t)dd * 64 + e4];
  }
  {
    int rr = tid >> 4, d4 = (tid & 15) * 4;
    *(float4*)&Ol[rr][d4] = *(const float4*)&oatt[((size_t)z * TT + t0 + rr) * DH + d4];
  }
  __syncthreads();
  const int rg = tid >> 6, e = tid & 63;
  float a0 = 0, a1 = 0, a2 = 0, a3 = 0;
#pragma unroll
  for (int dd = 0; dd < 64; ++dd) {
    float wv = Wl[dd][e];
    a0 += Ol[rg * 4 + 0][dd] * wv;
    a1 += Ol[rg * 4 + 1][dd] * wv;
    a2 += Ol[rg * 4 + 2][dd] * wv;
    a3 += Ol[rg * 4 + 3][dd] * wv;
  }
  size_t ob = ((size_t)b * TT + t0 + rg * 4) * DD + h * 64 + e;
  out[ob] = a0; out[ob + DD] = a1; out[ob + 2 * DD] = a2; out[ob + 3 * DD] = a3;
}

// ---------------------------------------------------------------------------
// ws layout (<=164 MB):
//  [0,4) qh  [4,8) ql  [8,12) kh  [12,16) kl   (oatt aliases [0,8) later)
//  [16,24) vs fp32   [24,28) vth  [28,32) vtl
//  [33,97) A fp16    ([33,41) doubles as xh/xl before k_qkv overwrites it)
//  [161,162.5) wth   [162.5,164) wtl
// ---------------------------------------------------------------------------
extern "C" void kernel_launch(void* const* d_in, const int* in_sizes, int n_in,
                              void* d_out, int out_size, void* d_ws, size_t ws_size,
                              hipStream_t stream)
{
  (void)in_sizes; (void)n_in; (void)out_size; (void)ws_size;
  const float* x  = (const float*)d_in[0];
  const float* wq = (const float*)d_in[1];
  const float* wk = (const float*)d_in[2];
  const float* wv = (const float*)d_in[3];
  const float* wo = (const float*)d_in[4];
  float* out = (float*)d_out;

  char* ws = (char*)d_ws;
  const size_t MB = 1024 * 1024;
  unsigned short* qh = (unsigned short*)(ws);
  unsigned short* ql = (unsigned short*)(ws + 4 * MB);
  unsigned short* kh = (unsigned short*)(ws + 8 * MB);
  unsigned short* kl = (unsigned short*)(ws + 12 * MB);
  float*          vs = (float*)(ws + 16 * MB);
  unsigned short* vth = (unsigned short*)(ws + 24 * MB);
  unsigned short* vtl = (unsigned short*)(ws + 28 * MB);
  float*          oatt = (float*)(ws);                    // aliases qh/ql (dead)
  _Float16*       A  = (_Float16*)(ws + 33 * MB);
  unsigned short* xh = (unsigned short*)(ws + 33 * MB);   // aliases A (dead by k_qkv)
  unsigned short* xl = (unsigned short*)(ws + 37 * MB);
  unsigned short* wth = (unsigned short*)(ws + 161 * MB);
  unsigned short* wtl = (unsigned short*)(ws + 161 * MB + 1536 * 1024);

  hipLaunchKernelGGL(k_prep, dim3(2048 + 192), dim3(256), 0, stream,
                     x, wq, wk, wv, xh, xl, wth, wtl);
  hipLaunchKernelGGL(k_proj_mfma, dim3(12, 64), dim3(256), 0, stream,
                     xh, xl, wth, wtl, qh, ql, kh, kl, vs);
  hipLaunchKernelGGL(k_qkv, dim3(1088 + 512), dim3(256), 0, stream,
                     qh, ql, kh, kl, A, vs, vth, vtl);
  hipLaunchKernelGGL(k_scan, dim3(512), dim3(1024), 0, stream, A);
  hipLaunchKernelGGL(k_pv, dim3(2048), dim3(64), 0, stream, A, vth, vtl, oatt);
  hipLaunchKernelGGL(k_oproj, dim3(64, 32), dim3(256), 0, stream,
                     oatt, wo, out);
}

// Round 13
// 213.819 us; speedup vs baseline: 1.6885x; 1.0288x over previous
//
#include <hip/hip_runtime.h>
#include <math.h>

#define BB    4
#define TT    1024
#define DD    512
#define NH    8
#define DH    64
#define BH    32          // BB*NH
#define INV_TAU 10.0f

typedef __attribute__((ext_vector_type(8))) short short8;
typedef __attribute__((ext_vector_type(4))) float f4;
typedef __attribute__((ext_vector_type(8))) _Float16 half8;

__device__ inline unsigned short f2bf(float f) {
  unsigned u = __float_as_uint(f);
  u += 0x7FFFu + ((u >> 16) & 1u);        // round-to-nearest-even
  return (unsigned short)(u >> 16);
}
__device__ inline float bf2f(unsigned short h) {
  return __uint_as_float(((unsigned)h) << 16);
}

// ---------------------------------------------------------------------------
// K0 "prep": merged split_x (blocks 0..2047) + split_wt (blocks 2048..2239).
// ---------------------------------------------------------------------------
__global__ __launch_bounds__(256) void k_prep(
    const float* __restrict__ x, const float* __restrict__ wq,
    const float* __restrict__ wk, const float* __restrict__ wv,
    unsigned short* __restrict__ xh, unsigned short* __restrict__ xl,
    unsigned short* __restrict__ wth, unsigned short* __restrict__ wtl)
{
  __shared__ float Wf[64][65];
  const int blk = blockIdx.x;
  const int tid = threadIdx.x;
  if (blk < 2048) {
    const int i = (blk * 256 + tid) * 4;
    float4 v = *(const float4*)&x[i];
    ushort4 h, l;
    h.x = f2bf(v.x); l.x = f2bf(v.x - bf2f(h.x));
    h.y = f2bf(v.y); l.y = f2bf(v.y - bf2f(h.y));
    h.z = f2bf(v.z); l.z = f2bf(v.z - bf2f(h.z));
    h.w = f2bf(v.w); l.w = f2bf(v.w - bf2f(h.w));
    *(ushort4*)&xh[i] = h;
    *(ushort4*)&xl[i] = l;
    return;
  }
  const int b = blk - 2048;                // 0..191
  const int ten = b >> 6;                  // 0..2
  const int r = b & 63;
  const int n0 = (r & 7) * 64, k0 = (r >> 3) * 64;
  const float* W = (ten == 0) ? wq : ((ten == 1) ? wk : wv);
#pragma unroll
  for (int p = 0; p < 4; ++p) {
    int kk = p * 16 + (tid >> 4);
    int nn = (tid & 15) * 4;
    float4 v = *(const float4*)&W[(size_t)(k0 + kk) * 512 + n0 + nn];
    Wf[kk][nn + 0] = v.x; Wf[kk][nn + 1] = v.y;
    Wf[kk][nn + 2] = v.z; Wf[kk][nn + 3] = v.w;
  }
  __syncthreads();
  const int n = tid >> 2, kq = tid & 3;
  size_t base = ((size_t)(ten * 512 + n0 + n)) * 512 + k0 + kq * 16;
#pragma unroll
  for (int jj = 0; jj < 4; ++jj) {
    ushort4 h, l;
    float f0 = Wf[kq * 16 + jj * 4 + 0][n];
    float f1 = Wf[kq * 16 + jj * 4 + 1][n];
    float f2 = Wf[kq * 16 + jj * 4 + 2][n];
    float f3 = Wf[kq * 16 + jj * 4 + 3][n];
    h.x = f2bf(f0); l.x = f2bf(f0 - bf2f(h.x));
    h.y = f2bf(f1); l.y = f2bf(f1 - bf2f(h.y));
    h.z = f2bf(f2); l.z = f2bf(f2 - bf2f(h.z));
    h.w = f2bf(f3); l.w = f2bf(f3 - bf2f(h.w));
    *(ushort4*)&wth[base + jj * 4] = h;
    *(ushort4*)&wtl[base + jj * 4] = l;
  }
}

// ---------------------------------------------------------------------------
// K1: QKV projection via bf16x3 MFMA + fused per-head softmax.
// ---------------------------------------------------------------------------
__global__ __launch_bounds__(256) void k_proj_mfma(
    const unsigned short* __restrict__ xh, const unsigned short* __restrict__ xl,
    const unsigned short* __restrict__ wth, const unsigned short* __restrict__ wtl,
    unsigned short* __restrict__ qh, unsigned short* __restrict__ ql,
    unsigned short* __restrict__ kh, unsigned short* __restrict__ kl,
    float* __restrict__ vs)
{
  __shared__ unsigned short Ah[64][40];
  __shared__ unsigned short Al[64][40];
  __shared__ unsigned short Bh[128][40];
  __shared__ unsigned short Bl[128][40];
  const int tid = threadIdx.x;
  const int n0g = blockIdx.x * 128;        // 0..1408
  const int m0 = blockIdx.y * 64;          // 0..4032
  const int w = tid >> 6, lane = tid & 63;
  const int mw = (w & 1) * 32, nw = (w >> 1) * 64;
  const int quad = lane >> 4, l16 = lane & 15;
  const int srow = tid >> 2;               // 0..63
  const int sk = (tid & 3) * 8;            // 0,8,16,24

  f4 acc[2][4] = {};

  for (int k0 = 0; k0 < DD; k0 += 32) {
    short8 a0 = *(const short8*)&xh[(size_t)(m0 + srow) * DD + k0 + sk];
    short8 a1 = *(const short8*)&xl[(size_t)(m0 + srow) * DD + k0 + sk];
    short8 b0 = *(const short8*)&wth[(size_t)(n0g + srow) * DD + k0 + sk];
    short8 b1 = *(const short8*)&wth[(size_t)(n0g + 64 + srow) * DD + k0 + sk];
    short8 b2 = *(const short8*)&wtl[(size_t)(n0g + srow) * DD + k0 + sk];
    short8 b3 = *(const short8*)&wtl[(size_t)(n0g + 64 + srow) * DD + k0 + sk];
    *(short8*)&Ah[srow][sk] = a0;
    *(short8*)&Al[srow][sk] = a1;
    *(short8*)&Bh[srow][sk] = b0;  *(short8*)&Bh[64 + srow][sk] = b1;
    *(short8*)&Bl[srow][sk] = b2;  *(short8*)&Bl[64 + srow][sk] = b3;
    __syncthreads();

    short8 fbh[4], fbl[4];
#pragma unroll
    for (int nt = 0; nt < 4; ++nt) {
      fbh[nt] = *(const short8*)&Bh[nw + nt * 16 + l16][quad * 8];
      fbl[nt] = *(const short8*)&Bl[nw + nt * 16 + l16][quad * 8];
    }
#pragma unroll
    for (int mt = 0; mt < 2; ++mt) {
      short8 fah = *(const short8*)&Ah[mw + mt * 16 + l16][quad * 8];
      short8 fal = *(const short8*)&Al[mw + mt * 16 + l16][quad * 8];
#pragma unroll
      for (int nt = 0; nt < 4; ++nt) {
        acc[mt][nt] = __builtin_amdgcn_mfma_f32_16x16x32_bf16(fah, fbh[nt], acc[mt][nt], 0, 0, 0);
        acc[mt][nt] = __builtin_amdgcn_mfma_f32_16x16x32_bf16(fah, fbl[nt], acc[mt][nt], 0, 0, 0);
        acc[mt][nt] = __builtin_amdgcn_mfma_f32_16x16x32_bf16(fal, fbh[nt], acc[mt][nt], 0, 0, 0);
      }
    }
    __syncthreads();
  }

  const int tensor = n0g >> 9;
  const int ncol = (n0g & 511) + nw;
  const int h = ncol >> 6;
#pragma unroll
  for (int mt = 0; mt < 2; ++mt) {
#pragma unroll
    for (int r = 0; r < 4; ++r) {
      float v0 = acc[mt][0][r], v1 = acc[mt][1][r];
      float v2 = acc[mt][2][r], v3 = acc[mt][3][r];
      float mx = fmaxf(fmaxf(v0, v1), fmaxf(v2, v3));
#pragma unroll
      for (int msk = 1; msk <= 8; msk <<= 1) mx = fmaxf(mx, __shfl_xor(mx, msk, 64));
      float e0 = __expf((v0 - mx) * INV_TAU);
      float e1 = __expf((v1 - mx) * INV_TAU);
      float e2 = __expf((v2 - mx) * INV_TAU);
      float e3 = __expf((v3 - mx) * INV_TAU);
      float sm = e0 + e1 + e2 + e3;
#pragma unroll
      for (int msk = 1; msk <= 8; msk <<= 1) sm += __shfl_xor(sm, msk, 64);
      float inv = 1.0f / sm;
      int row = m0 + mw + mt * 16 + quad * 4 + r;
      int b = row >> 10, t = row & 1023;
      size_t base = (((size_t)b * NH + h) * TT + t) * DH;
      float e[4] = {e0 * inv, e1 * inv, e2 * inv, e3 * inv};
      if (tensor == 2) {
#pragma unroll
        for (int c = 0; c < 4; ++c) vs[base + l16 + c * 16] = e[c];
      } else {
        unsigned short* oh = tensor ? kh : qh;
        unsigned short* ol = tensor ? kl : ql;
#pragma unroll
        for (int c = 0; c < 4; ++c) {
          unsigned short hh = f2bf(e[c]);
          oh[base + l16 + c * 16] = hh;
          ol[base + l16 + c * 16] = f2bf(e[c] - bf2f(hh));
        }
      }
    }
  }
}

// ---------------------------------------------------------------------------
// K2 "qkv": merged qk (blocks 0..1087) + vsplit (blocks 1088..1599).
// ---------------------------------------------------------------------------
__global__ __launch_bounds__(256) void k_qkv(
    const unsigned short* __restrict__ qh, const unsigned short* __restrict__ ql,
    const unsigned short* __restrict__ kh, const unsigned short* __restrict__ kl,
    _Float16* __restrict__ A, const float* __restrict__ vs,
    unsigned short* __restrict__ vth, unsigned short* __restrict__ vtl)
{
  __shared__ float Vf[64][65];
  const int tid = threadIdx.x;
  if (blockIdx.x >= 1088) {
    const int b = blockIdx.x - 1088;       // 0..511
    const int z = b & 31, t0 = (b >> 5) * 64;
#pragma unroll
    for (int it = 0; it < 4; ++it) {
      int tl = it * 16 + (tid >> 4);
      int d4 = (tid & 15) * 4;
      float4 v = *(const float4*)&vs[((size_t)z * TT + t0 + tl) * DH + d4];
      Vf[tl][d4 + 0] = v.x; Vf[tl][d4 + 1] = v.y;
      Vf[tl][d4 + 2] = v.z; Vf[tl][d4 + 3] = v.w;
    }
    __syncthreads();
#pragma unroll
    for (int it = 0; it < 8; ++it) {
      int d = it * 8 + (tid >> 5);
      int t = (tid & 31) * 2;
      float a0 = Vf[t][d], a1 = Vf[t + 1][d];
      unsigned short h0 = f2bf(a0), h1 = f2bf(a1);
      unsigned short l0 = f2bf(a0 - bf2f(h0)), l1 = f2bf(a1 - bf2f(h1));
      size_t o = ((size_t)z * DH + d) * TT + t0 + t;
      ushort2 hh; hh.x = h0; hh.y = h1;
      ushort2 ll; ll.x = l0; ll.y = l1;
      *(ushort2*)&vth[o] = hh;
      *(ushort2*)&vtl[o] = ll;
    }
    return;
  }
  const int gid = blockIdx.x * 4 + (tid >> 6);
  const int z = gid / 136;
  const int lx = gid - z * 136;
  int ti = (int)((sqrtf(8.0f * lx + 1.0f) - 1.0f) * 0.5f);
  while ((ti + 1) * (ti + 2) / 2 <= lx) ++ti;
  while (ti * (ti + 1) / 2 > lx) --ti;
  const int tj = lx - ti * (ti + 1) / 2;
  const int i0 = ti * 64, j0 = tj * 64;
  const int lane = tid & 63;
  const int quad = lane >> 4, l16 = lane & 15;
  const size_t zb = (size_t)z * TT * DH;

  short8 fbh[4][2], fbl[4][2];
#pragma unroll
  for (int nt = 0; nt < 4; ++nt)
#pragma unroll
    for (int ks = 0; ks < 2; ++ks) {
      size_t o = zb + (size_t)(j0 + nt * 16 + l16) * DH + ks * 32 + quad * 8;
      fbh[nt][ks] = *(const short8*)&kh[o];
      fbl[nt][ks] = *(const short8*)&kl[o];
    }

  f4 acc[4][4] = {};
#pragma unroll
  for (int mt = 0; mt < 4; ++mt) {
    short8 fah[2], fal[2];
#pragma unroll
    for (int ks = 0; ks < 2; ++ks) {
      size_t o = zb + (size_t)(i0 + mt * 16 + l16) * DH + ks * 32 + quad * 8;
      fah[ks] = *(const short8*)&qh[o];
      fal[ks] = *(const short8*)&ql[o];
    }
#pragma unroll
    for (int nt = 0; nt < 4; ++nt)
#pragma unroll
      for (int ks = 0; ks < 2; ++ks) {
        acc[mt][nt] = __builtin_amdgcn_mfma_f32_16x16x32_bf16(fah[ks], fbh[nt][ks], acc[mt][nt], 0, 0, 0);
        acc[mt][nt] = __builtin_amdgcn_mfma_f32_16x16x32_bf16(fah[ks], fbl[nt][ks], acc[mt][nt], 0, 0, 0);
        acc[mt][nt] = __builtin_amdgcn_mfma_f32_16x16x32_bf16(fal[ks], fbh[nt][ks], acc[mt][nt], 0, 0, 0);
      }
  }

  _Float16* Ab = A + (size_t)z * TT * TT;
#pragma unroll
  for (int mt = 0; mt < 4; ++mt)
#pragma unroll
    for (int nt = 0; nt < 4; ++nt)
#pragma unroll
      for (int r = 0; r < 4; ++r)
        Ab[(size_t)(i0 + mt * 16 + quad * 4 + r) * TT + j0 + nt * 16 + l16] =
            (_Float16)acc[mt][nt][r];
}

// ---------------------------------------------------------------------------
// K3: diagonal run-length scan — 3-pass, fp16 I/O, fp32 math.
// ---------------------------------------------------------------------------
__global__ __launch_bounds__(1024) void k_scan(_Float16* __restrict__ A)
{
  __shared__ float Ssum[16][64];
  __shared__ float Gmax[16][64];
  const int blk = blockIdx.x;              // 0..511
  const int p = blk >> 5;                  // 0..15
  const int xb = (p < 8) ? p : (23 - p);   // complementary pairing across CUs
  const int z = blk & 31;
  const int lane = threadIdx.x & 63;
  const int w = threadIdx.x >> 6;          // chunk 0..15
  _Float16* __restrict__ Ab = A + (size_t)z * TT * TT;
  const int dbase = xb * 64;
  const int d = dbase + lane;
  const int L = (TT - dbase) >> 4;         // 4..64 rows per chunk
  const int r0 = dbase + w * L;

  float S = 0.0f;
#pragma unroll 8
  for (int t = 0; t < L; ++t) {
    int i = r0 + t;
    size_t idx = (i >= d) ? ((size_t)i * (TT + 1) - d) : 0;
    float s = (float)Ab[idx];
    S += (i >= d) ? s : 0.0f;
  }
  Ssum[w][lane] = S;
  __syncthreads();

  float cs_in = 0.0f;
  for (int ww = 0; ww < w; ++ww) cs_in += Ssum[ww][lane];

  {
    float lcs = 0.0f, gm = 0.0f;
#pragma unroll 8
    for (int t = 0; t < L; ++t) {
      int i = r0 + t;
      size_t idx = (i >= d) ? ((size_t)i * (TT + 1) - d) : 0;
      float s0 = (float)Ab[idx];
      float s = (i >= d) ? s0 : 0.0f;
      lcs += s;
      gm = fmaxf(gm, (cs_in + lcs) * (1.0f - s));
    }
    Gmax[w][lane] = gm;
  }
  __syncthreads();

  float m = 0.0f;
  for (int ww = 0; ww < w; ++ww) m = fmaxf(m, Gmax[ww][lane]);

  {
    float lcs = 0.0f;
#pragma unroll 8
    for (int t = 0; t < L; ++t) {
      int i = r0 + t;
      bool ok = (i >= d);
      size_t idx = ok ? ((size_t)i * (TT + 1) - d) : 0;
      float s0 = (float)Ab[idx];
      float s = ok ? s0 : 0.0f;
      lcs += s;
      float cs = cs_in + lcs;
      m = fmaxf(m, cs * (1.0f - s));
      if (ok) Ab[idx] = (_Float16)(cs - m);
    }
  }
}

// ---------------------------------------------------------------------------
// K4: flash softmax(P)·V with SPLIT-K. Work item = (z, ti, band, K-chunk).
// ti>=8 tiles split at jt=8 into two independent chunks writing unnormalized
// partials (Opart + per-row m,l); ti<8 write final rows directly. 3072
// one-wave blocks; item mapping gives every CU exactly 68 jt-units under
// round-robin. Combine happens in k_oproj (fused).
// ---------------------------------------------------------------------------
__global__ __launch_bounds__(64) void k_pv(
    const _Float16* __restrict__ A, const unsigned short* __restrict__ vth,
    const unsigned short* __restrict__ vtl, float* __restrict__ oatt,
    float* __restrict__ Opart, float* __restrict__ ml)
{
  const int lane = threadIdx.x;
  const int quad = lane >> 4, l16 = lane & 15;
  const int blk = blockIdx.x;              // 0..3071
  const int z = blk & 31;
  const int item = blk >> 5;               // 0..95
  int ti, band, jt0, jt1, chunk;
  bool split;
  if (item < 32) {                         // len-8 first chunks of split tiles
    ti = 8 + (item >> 2); band = item & 3; jt0 = 0; jt1 = 8; chunk = 0; split = true;
  } else {
    int i2 = item - 32;                    // 0..63
    int l = 8 - (i2 >> 3);                 // 8..1 (descending length)
    int sub = i2 & 7;
    band = sub & 3;
    if (sub < 4) { ti = l + 7; jt0 = 8; jt1 = ti + 1; chunk = 1; split = true; }
    else         { ti = l - 1; jt0 = 0; jt1 = ti + 1; chunk = 0; split = false; }
  }
  const _Float16* Az = A + (size_t)z * TT * TT;
  const unsigned short* vh = vth + (size_t)z * DH * TT;
  const unsigned short* vl = vtl + (size_t)z * DH * TT;

  const int i0 = ti * 64;
  const int irow = i0 + band * 16 + l16;   // this lane's P-row
  const float invi = 1.0f / (float)(irow + 1);
  f4 acc[4] = {};
  float m_old = -3e38f, l_run = 0.0f;

  float posu[16];
#pragma unroll
  for (int u = 0; u < 16; ++u)
    posu[u] = (float)((u >> 3) * 32 + quad * 8 + (u & 7)) * invi;
  const float jstep = 64.0f * invi;
  float jtoff = (float)jt0 * jstep;

  for (int jt = jt0; jt < jt1; ++jt) {
    const bool masked = (jt == ti);
    float sc[16];
#pragma unroll
    for (int ks = 0; ks < 2; ++ks) {
      half8 hv = *(const half8*)&Az[(size_t)irow * TT + jt * 64 + ks * 32 + quad * 8];
#pragma unroll
      for (int u = 0; u < 8; ++u) sc[ks * 8 + u] = (float)hv[u];
    }
#pragma unroll
    for (int u = 0; u < 16; ++u) {
      float v = sc[u] + (jtoff + posu[u]);
      int j = jt * 64 + (u >> 3) * 32 + quad * 8 + (u & 7);
      sc[u] = (masked && j > irow) ? -3e38f : v;
    }
    float mt_ = sc[0];
#pragma unroll
    for (int u = 1; u < 16; ++u) mt_ = fmaxf(mt_, sc[u]);
    mt_ = fmaxf(mt_, __shfl_xor(mt_, 16, 64));
    mt_ = fmaxf(mt_, __shfl_xor(mt_, 32, 64));
    float m_new = fmaxf(m_old, mt_);
    float alpha = __expf((m_old - m_new) * INV_TAU);
    unsigned short ph[16], pl[16];
    float ls = 0.0f;
#pragma unroll
    for (int u = 0; u < 16; ++u) {
      float pvv = __expf((sc[u] - m_new) * INV_TAU);
      unsigned short hh = f2bf(pvv);
      ph[u] = hh; pl[u] = f2bf(pvv - bf2f(hh));
      ls += pvv;
    }
    ls += __shfl_xor(ls, 16, 64);
    ls += __shfl_xor(ls, 32, 64);
    l_run = l_run * alpha + ls;
    m_old = m_new;
#pragma unroll
    for (int rr = 0; rr < 4; ++rr) {
      float ar = __shfl(alpha, quad * 4 + rr, 64);
#pragma unroll
      for (int nt = 0; nt < 4; ++nt) acc[nt][rr] *= ar;
    }
#pragma unroll
    for (int ks = 0; ks < 2; ++ks) {
      short8 pah, pal;
#pragma unroll
      for (int u = 0; u < 8; ++u) { pah[u] = (short)ph[ks * 8 + u]; pal[u] = (short)pl[ks * 8 + u]; }
#pragma unroll
      for (int nt = 0; nt < 4; ++nt) {
        size_t vo = (size_t)(nt * 16 + l16) * TT + jt * 64 + ks * 32 + quad * 8;
        short8 fvh = *(const short8*)&vh[vo];
        short8 fvl = *(const short8*)&vl[vo];
        acc[nt] = __builtin_amdgcn_mfma_f32_16x16x32_bf16(pah, fvh, acc[nt], 0, 0, 0);
        acc[nt] = __builtin_amdgcn_mfma_f32_16x16x32_bf16(pah, fvl, acc[nt], 0, 0, 0);
        acc[nt] = __builtin_amdgcn_mfma_f32_16x16x32_bf16(pal, fvh, acc[nt], 0, 0, 0);
      }
    }
    jtoff += jstep;
  }

  if (!split) {
#pragma unroll
    for (int rr = 0; rr < 4; ++rr) {
      float lr = __shfl(l_run, quad * 4 + rr, 64);
      float inv = 1.0f / lr;
      int orow = i0 + band * 16 + quad * 4 + rr;
#pragma unroll
      for (int nt = 0; nt < 4; ++nt)
        oatt[((size_t)z * TT + orow) * DH + nt * 16 + l16] = acc[nt][rr] * inv;
    }
  } else {
    // unnormalized partial + per-row (m, l)
    if (quad == 0) {
      int prow = i0 + band * 16 + l16 - 512;
      size_t mo = (((size_t)chunk * 32 + z) * 512 + prow) * 2;
      ml[mo + 0] = m_old;
      ml[mo + 1] = l_run;
    }
#pragma unroll
    for (int rr = 0; rr < 4; ++rr) {
      int prow = i0 + band * 16 + quad * 4 + rr - 512;
      size_t po = (((size_t)chunk * 32 + z) * 512 + prow) * 64;
#pragma unroll
      for (int nt = 0; nt < 4; ++nt)
        Opart[po + nt * 16 + l16] = acc[nt][rr];
    }
  }
}

// ---------------------------------------------------------------------------
// K6: per-head output projection + fused split-K combine for rows >= 512.
// ---------------------------------------------------------------------------
__global__ __launch_bounds__(256) void k_oproj(
    const float* __restrict__ oatt, const float* __restrict__ wo,
    const float* __restrict__ Opart, const float* __restrict__ ml,
    float* __restrict__ out)
{
  __shared__ float Wl[64][64];
  __shared__ float Ol[16][64];
  const int z = blockIdx.y;                // b*NH + h
  const int t0 = blockIdx.x * 16;
  const int b = z >> 3, h = z & 7;
  const int tid = threadIdx.x;
  const float* wb = wo + (size_t)h * 64 * 64;
#pragma unroll
  for (int u = 0; u < 4; ++u) {
    int q = tid + 256 * u;
    int dd = q >> 4, e4 = (q & 15) * 4;
    *(float4*)&Wl[dd][e4] = *(const float4*)&wb[(size_t)dd * 64 + e4];
  }
  {
    int rr = tid >> 4, d4 = (tid & 15) * 4;
    int trow = t0 + rr;
    if (trow < 512) {
      *(float4*)&Ol[rr][d4] = *(const float4*)&oatt[((size_t)z * TT + trow) * DH + d4];
    } else {
      int pr = trow - 512;
      size_t m0o = (((size_t)0 * 32 + z) * 512 + pr) * 2;
      size_t m1o = (((size_t)1 * 32 + z) * 512 + pr) * 2;
      float m0 = ml[m0o], l0 = ml[m0o + 1];
      float m1 = ml[m1o], l1 = ml[m1o + 1];
      float mm = fmaxf(m0, m1);
      float w0 = __expf((m0 - mm) * INV_TAU);
      float w1 = __expf((m1 - mm) * INV_TAU);
      float inv = 1.0f / (l0 * w0 + l1 * w1);
      float4 o0 = *(const float4*)&Opart[(((size_t)0 * 32 + z) * 512 + pr) * 64 + d4];
      float4 o1 = *(const float4*)&Opart[(((size_t)1 * 32 + z) * 512 + pr) * 64 + d4];
      Ol[rr][d4 + 0] = (o0.x * w0 + o1.x * w1) * inv;
      Ol[rr][d4 + 1] = (o0.y * w0 + o1.y * w1) * inv;
      Ol[rr][d4 + 2] = (o0.z * w0 + o1.z * w1) * inv;
      Ol[rr][d4 + 3] = (o0.w * w0 + o1.w * w1) * inv;
    }
  }
  __syncthreads();
  const int rg = tid >> 6, e = tid & 63;
  float a0 = 0, a1 = 0, a2 = 0, a3 = 0;
#pragma unroll
  for (int dd = 0; dd < 64; ++dd) {
    float wv = Wl[dd][e];
    a0 += Ol[rg * 4 + 0][dd] * wv;
    a1 += Ol[rg * 4 + 1][dd] * wv;
    a2 += Ol[rg * 4 + 2][dd] * wv;
    a3 += Ol[rg * 4 + 3][dd] * wv;
  }
  size_t ob = ((size_t)b * TT + t0 + rg * 4) * DD + h * 64 + e;
  out[ob] = a0; out[ob + DD] = a1; out[ob + 2 * DD] = a2; out[ob + 3 * DD] = a3;
}

// ---------------------------------------------------------------------------
// ws layout (<=164 MB):
//  [0,4) qh  [4,8) ql  [8,12) kh  [12,16) kl   (oatt aliases [0,8) later)
//  [16,24) vs fp32   [24,28) vth  [28,32) vtl
//  [33,97) A fp16    ([33,41) doubles as xh/xl before k_qkv overwrites it)
//  [97,113) Opart    [113,113.25) ml
//  [161,162.5) wth   [162.5,164) wtl
// ---------------------------------------------------------------------------
extern "C" void kernel_launch(void* const* d_in, const int* in_sizes, int n_in,
                              void* d_out, int out_size, void* d_ws, size_t ws_size,
                              hipStream_t stream)
{
  (void)in_sizes; (void)n_in; (void)out_size; (void)ws_size;
  const float* x  = (const float*)d_in[0];
  const float* wq = (const float*)d_in[1];
  const float* wk = (const float*)d_in[2];
  const float* wv = (const float*)d_in[3];
  const float* wo = (const float*)d_in[4];
  float* out = (float*)d_out;

  char* ws = (char*)d_ws;
  const size_t MB = 1024 * 1024;
  unsigned short* qh = (unsigned short*)(ws);
  unsigned short* ql = (unsigned short*)(ws + 4 * MB);
  unsigned short* kh = (unsigned short*)(ws + 8 * MB);
  unsigned short* kl = (unsigned short*)(ws + 12 * MB);
  float*          vs = (float*)(ws + 16 * MB);
  unsigned short* vth = (unsigned short*)(ws + 24 * MB);
  unsigned short* vtl = (unsigned short*)(ws + 28 * MB);
  float*          oatt = (float*)(ws);                    // aliases qh/ql (dead)
  _Float16*       A  = (_Float16*)(ws + 33 * MB);
  unsigned short* xh = (unsigned short*)(ws + 33 * MB);   // aliases A (dead by k_qkv)
  unsigned short* xl = (unsigned short*)(ws + 37 * MB);
  float*          Opart = (float*)(ws + 97 * MB);
  float*          ml = (float*)(ws + 113 * MB);
  unsigned short* wth = (unsigned short*)(ws + 161 * MB);
  unsigned short* wtl = (unsigned short*)(ws + 161 * MB + 1536 * 1024);

  hipLaunchKernelGGL(k_prep, dim3(2048 + 192), dim3(256), 0, stream,
                     x, wq, wk, wv, xh, xl, wth, wtl);
  hipLaunchKernelGGL(k_proj_mfma, dim3(12, 64), dim3(256), 0, stream,
                     xh, xl, wth, wtl, qh, ql, kh, kl, vs);
  hipLaunchKernelGGL(k_qkv, dim3(1088 + 512), dim3(256), 0, stream,
                     qh, ql, kh, kl, A, vs, vth, vtl);
  hipLaunchKernelGGL(k_scan, dim3(512), dim3(1024), 0, stream, A);
  hipLaunchKernelGGL(k_pv, dim3(3072), dim3(64), 0, stream, A, vth, vtl,
                     oatt, Opart, ml);
  hipLaunchKernelGGL(k_oproj, dim3(64, 32), dim3(256), 0, stream,
                     oatt, wo, Opart, ml, out);
}